// Round 8
// baseline (1654.500 us; speedup 1.0000x reference)
//
#include <hip/hip_runtime.h>
#include <hip/hip_bf16.h>
#include <math.h>

#define S_LEN 512
#define B_SZ  256
#define E_DIM 128
#define HHID  128
#define G4    512   // 4*HH
#define T_TAG 9
#define NR    (S_LEN * B_SZ)   // r = s*256 + b
#define VOCAB 5001
#define VOCABP 5008   // padded to 16 for pxv tiling

typedef __attribute__((ext_vector_type(8))) short bf16x8;
typedef __attribute__((ext_vector_type(4))) float f32x4;
typedef __attribute__((ext_vector_type(8))) unsigned short u16x8;

__device__ __forceinline__ float bf2f(__hip_bfloat16 v) { return __bfloat162float(v); }
__device__ __forceinline__ float scrub0(float v) {       // inf/nan -> 0
    unsigned u = __float_as_uint(v);
    return (((u >> 23) & 0xFFu) == 0xFFu) ? 0.f : v;
}
__device__ __forceinline__ float frcp(float x) { return __builtin_amdgcn_rcpf(x); }
__device__ __forceinline__ float fsig(float x) { return frcp(1.f + __expf(-x)); }
__device__ __forceinline__ float ftanh(float x) {
    return 1.f - 2.f * frcp(1.f + __expf(2.f * x));
}

// ---- .bss scratch ----
__device__ __hip_bfloat16 g_emb[VOCAB * E_DIM];
__device__ __hip_bfloat16 g_wih[2][G4 * E_DIM];    // rows permuted: n' = 4u+g
__device__ __hip_bfloat16 g_whh2[2][G4 * HHID];    // rows permuted: n' = 4u+g
__device__ __align__(16) float g_bias[2][G4];      // permuted
__device__ float g_wout[T_TAG * 256];
__device__ float g_bout[T_TAG];
__device__ float g_trans[T_TAG * T_TAG];
__device__ float g_start[T_TAG];
__device__ float g_end[T_TAG];
__device__ float g_maskf[B_SZ * S_LEN];
__device__ float g_em[(long)NR * T_TAG];
__device__ __align__(16) float g_hs[2][(long)NR * HHID];  // [(s*16+bg)*128+u]*16+m
// pxv[dir][v][u][g] = bias + Wih'@emb[v] for every VOCAB token (20.5 MB,
// L3-resident). Scan gathers by token id — replaces the 512 MiB px stream.
__device__ __align__(16) float g_pxv[(long)2 * VOCABP * 128 * 4];

// -------------------------------------------------------------------------
// Canonicalize inputs (bf16/fp32 autodetect via mask). Gate permutation:
// row n' = 4u+g  <->  original torch gate row g*128+u.
// Also zero-fills the output buffer (folded fill_out).
// Embedding loop vectorized (ushort8 scrub for bf16 / float4 for f32).
// -------------------------------------------------------------------------
__global__ __launch_bounds__(256) void convert_kernel(
    const void* mask, const void* emb,
    const void* wih_f, const void* whh_f, const void* bih_f, const void* bhh_f,
    const void* wih_b, const void* whh_b, const void* bih_b, const void* bhh_b,
    const void* wout, const void* bout, const void* trans,
    const void* startt, const void* endt, float* out, int out_size)
{
    const bool isb = (((const unsigned*)mask)[0] == 0x3F803F80u);
    auto ldf = [&](const void* p, long i) -> float {
        float v = isb ? bf2f(((const __hip_bfloat16*)p)[i]) : ((const float*)p)[i];
        return scrub0(v);
    };
    const long tid0   = (long)blockIdx.x * blockDim.x + threadIdx.x;
    const long stride = (long)gridDim.x * blockDim.x;

    for (long i = tid0; i < out_size; i += stride) out[i] = 0.f;

    // embedding: vectorized 8-wide (VOCAB*E_DIM = 640128, divisible by 8)
    if (isb) {
        const u16x8* src = (const u16x8*)emb;
        u16x8* dst = (u16x8*)g_emb;
        for (long i = tid0; i < (long)VOCAB * E_DIM / 8; i += stride) {
            u16x8 v = src[i];
            #pragma unroll
            for (int j = 0; j < 8; j++)
                if (((v[j] >> 7) & 0xFFu) == 0xFFu) v[j] = 0;
            dst[i] = v;
        }
    } else {
        const float4* src = (const float4*)emb;
        for (long i = tid0; i < (long)VOCAB * E_DIM / 4; i += stride) {
            const float4 v = src[i];
            __hip_bfloat16* d = &g_emb[i * 4];
            d[0] = __float2bfloat16(scrub0(v.x));
            d[1] = __float2bfloat16(scrub0(v.y));
            d[2] = __float2bfloat16(scrub0(v.z));
            d[3] = __float2bfloat16(scrub0(v.w));
        }
    }
    for (long i = tid0; i < (long)G4 * E_DIM; i += stride) {
        const int np = (int)(i >> 7), e = (int)(i & 127);
        const int g = np & 3, u = np >> 2;
        const long src = (long)(g * 128 + u) * E_DIM + e;
        g_wih[0][i] = __float2bfloat16(ldf(wih_f, src));
        g_wih[1][i] = __float2bfloat16(ldf(wih_b, src));
    }
    for (long i = tid0; i < (long)G4 * HHID; i += stride) {
        const int np = (int)(i >> 7), k = (int)(i & 127);
        const int g = np & 3, u = np >> 2;
        const long src = (long)(g * 128 + u) * HHID + k;
        g_whh2[0][i] = __float2bfloat16(ldf(whh_f, src));
        g_whh2[1][i] = __float2bfloat16(ldf(whh_b, src));
    }
    for (long i = tid0; i < G4; i += stride) {
        const int g = (int)i & 3, u = (int)i >> 2;
        const long src = g * 128 + u;
        g_bias[0][i] = ldf(bih_f, src) + ldf(bhh_f, src);
        g_bias[1][i] = ldf(bih_b, src) + ldf(bhh_b, src);
    }
    for (long i = tid0; i < T_TAG * 256; i += stride) g_wout[i] = ldf(wout, i);
    for (long i = tid0; i < T_TAG * T_TAG; i += stride) g_trans[i] = ldf(trans, i);
    for (long i = tid0; i < T_TAG; i += stride) {
        g_bout[i]  = ldf(bout, i);
        g_start[i] = ldf(startt, i);
        g_end[i]   = ldf(endt, i);
    }
    for (long i = tid0; i < (long)B_SZ * S_LEN; i += stride)
        g_maskf[i] = ldf(mask, i);
}

// -------------------------------------------------------------------------
// Per-VOCAB input projection: pxv[dir][v] = bias + Wih'@emb[v]^T. MFMA
// columns = 16 tokens per block. Bit-exact same fragments/accumulation order
// as the old per-(s,b) px compute — gathering by token reproduces px exactly.
// Grid (313 token-groups, 2 dir), 512 threads (8 waves x 4 tiles).
// -------------------------------------------------------------------------
__global__ __launch_bounds__(512, 2) void pxv_gemm()
{
    const int grp = blockIdx.x, dir = blockIdx.y;
    const int tid  = threadIdx.x;
    const int lane = tid & 63, wv = tid >> 6;
    const int m16  = lane & 15, quad = lane >> 4;

    bf16x8 V[4][4];
    f32x4 bias4[4];
    #pragma unroll
    for (int t = 0; t < 4; t++) {
        const int np = (wv * 4 + t) * 16 + m16;
        #pragma unroll
        for (int kk = 0; kk < 4; kk++)
            V[t][kk] = *(const bf16x8*)&g_wih[dir][(long)np * E_DIM + kk * 32 + quad * 8];
        const int u = 16 * wv + 4 * t + quad;
        const float4 b4 = *(const float4*)&g_bias[dir][4 * u];
        bias4[t] = (f32x4){b4.x, b4.y, b4.z, b4.w};
    }
    const int v  = grp * 16 + m16;
    const int vv = (v < VOCAB) ? v : 0;
    bf16x8 E[4];
    #pragma unroll
    for (int kk = 0; kk < 4; kk++)
        E[kk] = *(const bf16x8*)&g_emb[(long)vv * E_DIM + kk * 32 + quad * 8];
    #pragma unroll
    for (int t = 0; t < 4; t++) {
        f32x4 px = bias4[t];
        #pragma unroll
        for (int kk = 0; kk < 4; kk++)
            px = __builtin_amdgcn_mfma_f32_16x16x32_bf16(V[t][kk], E[kk], px, 0, 0, 0);
        const int u = 16 * wv + 4 * t + quad;
        if (v < VOCAB)
            *(f32x4*)&g_pxv[((long)(dir * VOCABP + v) * 128 + u) * 4] = px;
    }
}

// -------------------------------------------------------------------------
// DUAL-DIRECTION fused MFMA scan: one block per bg (grid 16), 8 waves, each
// wave holds BOTH dirs' Whh fragments and runs [dir0 phase][dir1 phase][bar]
// per superstep. The two recurrences are independent: dir1's MFMAs issue
// while dir0's activation chain occupies the trans pipe (and vice versa),
// and the barrier count per step-equivalent halves — attacking the ~1200
// cy/step lockstep stall that was invariant to wave count / LDS / prefetch.
// px: ONE register set per dir (doubles as MFMA accumulator), refilled at
// phase end, in flight across the other dir's phase + barrier (~900 cy).
// xO token table staged once, shared by both dirs.
// Per-dir accumulation order identical to previous rounds — bit-exact.
// VGPR budget ~225 (W 128 + px 32 + H 32 + c 8 + misc) -> 2 waves/SIMD.
// -------------------------------------------------------------------------
#define PHASE(HBD, RD, PX, W, cc, hsp, sev, STEPD, HSD, pxvL)                  \
  {                                                                            \
    const int wr_ = (RD) ^ 1;                                                  \
    /* early: offset+address for next-step gather (latency hides below) */     \
    int seN_ = sev + (STEPD);                                                  \
    seN_ = seN_ < 0 ? 0 : (seN_ > S_LEN - 1 ? S_LEN - 1 : seN_);               \
    const float* pf_ = pxvL + xO[seN_ * 16 + m16];                             \
    bf16x8 Hh_[4], Hl_[4];                                                     \
    _Pragma("unroll")                                                          \
    for (int kk = 0; kk < 4; kk++) {                                           \
        const int off_ = ((kk * 4 + quad) * 16 + m16) * 8;                     \
        Hh_[kk] = *(const bf16x8*)&hB[HBD][RD][0][off_];                       \
        Hl_[kk] = *(const bf16x8*)&hB[HBD][RD][1][off_];                       \
    }                                                                          \
    _Pragma("unroll")                                                          \
    for (int t = 0; t < 4; t++) {                                              \
        _Pragma("unroll")                                                      \
        for (int kk = 0; kk < 4; kk++) {                                       \
            PX[t] = __builtin_amdgcn_mfma_f32_16x16x32_bf16(W[t][kk], Hh_[kk], PX[t], 0, 0, 0); \
            PX[t] = __builtin_amdgcn_mfma_f32_16x16x32_bf16(W[t][kk], Hl_[kk], PX[t], 0, 0, 0); \
        }                                                                      \
    }                                                                          \
    _Pragma("unroll")                                                          \
    for (int t = 0; t < 4; t++) {                                              \
        const float iv = fsig(PX[t][0]);                                       \
        const float fv = fsig(PX[t][1]);                                       \
        const float gv = ftanh(PX[t][2]);                                      \
        const float ov = fsig(PX[t][3]);                                       \
        cc[t] = fv * cc[t] + iv * gv;                                          \
        const float h = ov * ftanh(cc[t]);                                     \
        const int u = 16 * wv + 4 * t + quad;                                  \
        const unsigned ub = __float_as_uint(h);                                \
        const unsigned hb_ = ub >> 16;                                         \
        const float hif = __uint_as_float(ub & 0xFFFF0000u);                   \
        const unsigned lb_ = __float_as_uint(h - hif) >> 16;                   \
        const int ha = (u >> 3) * 128 + m16 * 8 + (u & 7);                     \
        hB[HBD][wr_][0][ha] = (unsigned short)hb_;                             \
        hB[HBD][wr_][1][ha] = (unsigned short)lb_;                             \
        hsp[t * 64] = h;                                                       \
    }                                                                          \
    {   /* refill PX for next step — rides across other-dir phase + barrier */ \
        PX[0] = *(const f32x4*)(pf_ + 0);                                      \
        PX[1] = *(const f32x4*)(pf_ + 16);                                     \
        PX[2] = *(const f32x4*)(pf_ + 32);                                     \
        PX[3] = *(const f32x4*)(pf_ + 48);                                     \
    }                                                                          \
    hsp += (HSD); sev += (STEPD);                                              \
  }

#define SCAN_BAR()                                                             \
    asm volatile("s_waitcnt lgkmcnt(0)" ::: "memory");                         \
    __builtin_amdgcn_sched_barrier(0);                                         \
    __builtin_amdgcn_s_barrier();                                              \
    __builtin_amdgcn_sched_barrier(0);

__global__ __launch_bounds__(512, 2) void scan_mfma(const int* __restrict__ x)
{
    __shared__ __align__(16) unsigned short hB[2][2][2][2048];  // 32 KB [dir][par][hi/lo]
    __shared__ int xO[S_LEN * 16];   // token * 512 (pxv element offset), 32 KB

    const int bg = blockIdx.x;                       // grid = 16
    const int tid  = threadIdx.x;
    const int lane = tid & 63, wv = tid >> 6;        // wv 0..7
    const int m16  = lane & 15, quad = lane >> 4;

    // persistent A fragments for BOTH dirs: Whh' rows (4 tiles x 16 rows)
    bf16x8 W0[4][4], W1[4][4];
    #pragma unroll
    for (int t = 0; t < 4; t++) {
        const int np = (wv * 4 + t) * 16 + m16;
        #pragma unroll
        for (int kk = 0; kk < 4; kk++) {
            W0[t][kk] = *(const bf16x8*)&g_whh2[0][(long)np * HHID + kk * 32 + quad * 8];
            W1[t][kk] = *(const bf16x8*)&g_whh2[1][(long)np * HHID + kk * 32 + quad * 8];
        }
    }
    {   // stage token offsets ONCE (shared by both dirs)
        const bool x64 = ((x[1] | x[3] | x[5] | x[7]) == 0);
        for (int i = tid; i < S_LEN * 16; i += 512) {
            const int s = i >> 4, m = i & 15;
            const int ii = (bg * 16 + m) * S_LEN + s;
            int tok = x64 ? x[2 * ii] : x[ii];
            tok = (unsigned)tok < VOCAB ? tok : 0;
            xO[i] = tok * 512;
        }
    }
    for (int i = tid; i < 2 * 2 * 2 * 2048; i += 512) ((unsigned short*)hB)[i] = 0;
    float c0[4] = {0.f, 0.f, 0.f, 0.f};
    float c1[4] = {0.f, 0.f, 0.f, 0.f};
    __syncthreads();

    const int u0 = 16 * wv + quad;

    // pxv lane bases per dir: element ((dir*VOCABP + v)*128 + u)*4
    const float* pxvL0 = &g_pxv[u0 * 4];
    const float* pxvL1 = &g_pxv[(long)VOCABP * 512 + u0 * 4];

    // initial px gathers: dir0 step 0, dir1 step 511
    f32x4 px0[4], px1[4];
    {
        const int o0 = xO[0 * 16 + m16];
        const int o1 = xO[(S_LEN - 1) * 16 + m16];
        #pragma unroll
        for (int t = 0; t < 4; t++) {
            px0[t] = *(const f32x4*)(pxvL0 + o0 + 16 * t);
            px1[t] = *(const f32x4*)(pxvL1 + o1 + 16 * t);
        }
    }

    // hs store bases: dir0 at s=0 (delta +32768), dir1 at s=511 (delta -32768)
    float* hsp0 = &g_hs[0][((long)(0 * 16 + bg) * 128 + u0) * 16 + m16];
    float* hsp1 = &g_hs[1][((long)((S_LEN - 1) * 16 + bg) * 128 + u0) * 16 + m16];

    int sev0 = 0, sev1 = S_LEN - 1;

    for (int it = 0; it < S_LEN; it += 2) {
        PHASE(0, 0, px0, W0, c0, hsp0, sev0, +1, (long)32768, pxvL0)
        PHASE(1, 0, px1, W1, c1, hsp1, sev1, -1, (long)-32768, pxvL1)
        SCAN_BAR()
        PHASE(0, 1, px0, W0, c0, hsp0, sev0, +1, (long)32768, pxvL0)
        PHASE(1, 1, px1, W1, c1, hsp1, sev1, -1, (long)-32768, pxvL1)
        SCAN_BAR()
    }
}

// -------------------------------------------------------------------------
// Bulk emission from hs layout: block = (s,bg) tile [128u x 16m], staged in
// LDS; thread (m, j<9) dots 256-k. em[r*9+j] includes bout.
// -------------------------------------------------------------------------
__global__ __launch_bounds__(256, 4) void emission_kernel()
{
    __shared__ float hfL[2048], hbL[2048];
    __shared__ float Wsh[T_TAG][256];
    __shared__ float bo[T_TAG];
    const int tid = threadIdx.x, blk = blockIdx.x;   // 0..8191 = s*16+bg
    for (int i = tid; i < T_TAG * 256; i += 256) Wsh[i >> 8][i & 255] = g_wout[i];
    if (tid < T_TAG) bo[tid] = g_bout[tid];
    const float* hf = &g_hs[0][(long)blk * 2048];
    const float* hb = &g_hs[1][(long)blk * 2048];
    for (int i = tid; i < 2048; i += 256) { hfL[i] = hf[i]; hbL[i] = hb[i]; }
    __syncthreads();

    const int m = tid & 15, j = tid >> 4;
    if (j < T_TAG) {
        float acc = bo[j];
        #pragma unroll 4
        for (int u = 0; u < 128; u++)
            acc += hfL[u * 16 + m] * Wsh[j][u] + hbL[u * 16 + m] * Wsh[j][128 + u];
        const int r = (blk >> 4) * 256 + (blk & 15) * 16 + m;   // s*256 + b
        g_em[(long)r * T_TAG + j] = scrub0(acc);
    }
}

// -------------------------------------------------------------------------
// Viterbi: 1 wave per BLOCK (grid 256 -> 1 block/CU). Lanes 0..8 = tags,
// score broadcast via wave shfl. Strict-> argmax = jnp first-max.
// -------------------------------------------------------------------------
__global__ __launch_bounds__(64, 1)
void viterbi_kernel(float* __restrict__ out, int out_size)
{
    __shared__ unsigned char bp[S_LEN][T_TAG];
    const int lane = threadIdx.x;
    const int b  = blockIdx.x;
    const int jj = (lane < T_TAG) ? lane : 0;

    float tcol[T_TAG];
    #pragma unroll
    for (int i = 0; i < T_TAG; i++) tcol[i] = g_trans[i * T_TAG + jj];

    float score[T_TAG];
    {
        const float m0 = g_maskf[b * S_LEN + 0];
        #pragma unroll
        for (int i = 0; i < T_TAG; i++)
            score[i] = g_start[i] + g_em[(long)b * T_TAG + i] * m0;
    }
    float e = g_em[((long)1 * B_SZ + b) * T_TAG + jj];
    float m = g_maskf[b * S_LEN + 1];

    for (int s = 1; s < S_LEN; s++) {
        float en = 0.f, mn = 0.f;
        if (s + 1 < S_LEN) {   // prefetch next step
            en = g_em[((long)(s + 1) * B_SZ + b) * T_TAG + jj];
            mn = g_maskf[b * S_LEN + s + 1];
        }
        float best = score[0] + tcol[0];
        int arg = 0;
        #pragma unroll
        for (int i = 1; i < T_TAG; i++) {
            const float cnd = score[i] + tcol[i];
            if (cnd > best) { best = cnd; arg = i; }
        }
        float ns; int nbp;
        if (m > 0.f) { ns = best + e * m; nbp = arg; }
        else         { ns = score[jj];    nbp = jj;  }
        if (lane < T_TAG) bp[s][jj] = (unsigned char)nbp;
        #pragma unroll
        for (int i = 0; i < T_TAG; i++) score[i] = __shfl(ns, i, 64);
        e = en; m = mn;
    }
    #pragma unroll
    for (int i = 0; i < T_TAG; i++) score[i] += g_end[i];

    __syncthreads();   // bp visible for backtrace

    if (lane == 0) {
        float bs = score[0]; int last = 0;
        #pragma unroll
        for (int i = 1; i < T_TAG; i++)
            if (score[i] > bs) { bs = score[i]; last = i; }
        {
            const unsigned u = __float_as_uint(bs);
            if (((u >> 23) & 0xFFu) == 0xFFu) bs = -100.f;
        }
        if ((long)B_SZ * S_LEN + b < out_size)
            out[(long)B_SZ * S_LEN + b] = bs;
        int tag = last;
        if (tag < 0) tag = 0; if (tag > 8) tag = 8;
        out[(long)b * S_LEN + (S_LEN - 1)] = (float)tag;
        for (int s2 = S_LEN - 1; s2 >= 1; s2--) {
            tag = bp[s2][tag];
            if (tag < 0) tag = 0; if (tag > 8) tag = 8;
            out[(long)b * S_LEN + (s2 - 1)] = (float)tag;
        }
    }
}

// -------------------------------------------------------------------------
extern "C" void kernel_launch(void* const* d_in, const int* in_sizes, int n_in,
                              void* d_out, int out_size, void* d_ws, size_t ws_size,
                              hipStream_t stream) {
    const int* x = (const int*)d_in[0];
    float* out = (float*)d_out;

    convert_kernel<<<512, 256, 0, stream>>>(
        d_in[1], d_in[2], d_in[3], d_in[4], d_in[5], d_in[6],
        d_in[7], d_in[8], d_in[9], d_in[10], d_in[11], d_in[12],
        d_in[13], d_in[14], d_in[15], out, out_size);
    pxv_gemm<<<dim3((VOCABP / 16), 2), 512, 0, stream>>>();
    scan_mfma<<<16, 512, 0, stream>>>(x);
    emission_kernel<<<8192, 256, 0, stream>>>();
    viterbi_kernel<<<256, 64, 0, stream>>>(out, out_size);
}

// Round 10
// 931.550 us; speedup vs baseline: 1.7761x; 1.7761x over previous
//
#include <hip/hip_runtime.h>
#include <hip/hip_bf16.h>
#include <math.h>

#define S_LEN 512
#define B_SZ  256
#define E_DIM 128
#define HHID  128
#define G4    512   // 4*HH
#define T_TAG 9
#define VOCAB 5001
#define VOCABP 5008   // padded to 16 for pxv tiling
#define EMP_SZ (512L * 16 * 256)   // per-partial emission plane (s,bg,16j,16m)

typedef __attribute__((ext_vector_type(8))) short bf16x8;
typedef __attribute__((ext_vector_type(4))) float f32x4;
typedef __attribute__((ext_vector_type(8))) unsigned short u16x8;

__device__ __forceinline__ float bf2f(__hip_bfloat16 v) { return __bfloat162float(v); }
__device__ __forceinline__ float scrub0(float v) {       // inf/nan -> 0
    unsigned u = __float_as_uint(v);
    return (((u >> 23) & 0xFFu) == 0xFFu) ? 0.f : v;
}
__device__ __forceinline__ float frcp(float x) { return __builtin_amdgcn_rcpf(x); }
__device__ __forceinline__ float fsig(float x) { return frcp(1.f + __expf(-x)); }
__device__ __forceinline__ float ftanh(float x) {
    return 1.f - 2.f * frcp(1.f + __expf(2.f * x));
}

// ---- .bss scratch ----
__device__ __hip_bfloat16 g_emb[VOCAB * E_DIM];
__device__ __hip_bfloat16 g_wih[2][G4 * E_DIM];    // rows permuted: n' = 4u+g
__device__ __hip_bfloat16 g_whh2[2][G4 * HHID];    // rows permuted: n' = 4u+g
__device__ __align__(16) float g_bias[2][G4];      // permuted
__device__ float g_wout[T_TAG * 256];
__device__ float g_bout[T_TAG];
__device__ float g_trans[T_TAG * T_TAG];
__device__ float g_start[T_TAG];
__device__ float g_end[T_TAG];
__device__ float g_maskf[B_SZ * S_LEN];
// pxv[dir][v][u][g] = bias + Wih'@emb[v] for every VOCAB token (20.5 MB,
// L3-resident). Scan gathers by token id.
__device__ __align__(16) float g_pxv[(long)2 * VOCABP * 128 * 4];
// Fused-emission partials: [dir*4 + part][(s*16+bg)*256 + j*16 + m].
// part = cross term {WhiHh, WhiHl, WloHh, WloHl}; viterbi sums the 8 planes.
__device__ __align__(16) float g_emp[8][EMP_SZ];   // 67 MB

// -------------------------------------------------------------------------
// Canonicalize inputs (bf16/fp32 autodetect via mask). Gate permutation:
// row n' = 4u+g  <->  original torch gate row g*128+u.
// Also zero-fills the output buffer (folded fill_out).
// -------------------------------------------------------------------------
__global__ __launch_bounds__(256) void convert_kernel(
    const void* mask, const void* emb,
    const void* wih_f, const void* whh_f, const void* bih_f, const void* bhh_f,
    const void* wih_b, const void* whh_b, const void* bih_b, const void* bhh_b,
    const void* wout, const void* bout, const void* trans,
    const void* startt, const void* endt, float* out, int out_size)
{
    const bool isb = (((const unsigned*)mask)[0] == 0x3F803F80u);
    auto ldf = [&](const void* p, long i) -> float {
        float v = isb ? bf2f(((const __hip_bfloat16*)p)[i]) : ((const float*)p)[i];
        return scrub0(v);
    };
    const long tid0   = (long)blockIdx.x * blockDim.x + threadIdx.x;
    const long stride = (long)gridDim.x * blockDim.x;

    for (long i = tid0; i < out_size; i += stride) out[i] = 0.f;

    // embedding: vectorized 8-wide (VOCAB*E_DIM = 640128, divisible by 8)
    if (isb) {
        const u16x8* src = (const u16x8*)emb;
        u16x8* dst = (u16x8*)g_emb;
        for (long i = tid0; i < (long)VOCAB * E_DIM / 8; i += stride) {
            u16x8 v = src[i];
            #pragma unroll
            for (int j = 0; j < 8; j++)
                if (((v[j] >> 7) & 0xFFu) == 0xFFu) v[j] = 0;
            dst[i] = v;
        }
    } else {
        const float4* src = (const float4*)emb;
        for (long i = tid0; i < (long)VOCAB * E_DIM / 4; i += stride) {
            const float4 v = src[i];
            __hip_bfloat16* d = &g_emb[i * 4];
            d[0] = __float2bfloat16(scrub0(v.x));
            d[1] = __float2bfloat16(scrub0(v.y));
            d[2] = __float2bfloat16(scrub0(v.z));
            d[3] = __float2bfloat16(scrub0(v.w));
        }
    }
    for (long i = tid0; i < (long)G4 * E_DIM; i += stride) {
        const int np = (int)(i >> 7), e = (int)(i & 127);
        const int g = np & 3, u = np >> 2;
        const long src = (long)(g * 128 + u) * E_DIM + e;
        g_wih[0][i] = __float2bfloat16(ldf(wih_f, src));
        g_wih[1][i] = __float2bfloat16(ldf(wih_b, src));
    }
    for (long i = tid0; i < (long)G4 * HHID; i += stride) {
        const int np = (int)(i >> 7), k = (int)(i & 127);
        const int g = np & 3, u = np >> 2;
        const long src = (long)(g * 128 + u) * HHID + k;
        g_whh2[0][i] = __float2bfloat16(ldf(whh_f, src));
        g_whh2[1][i] = __float2bfloat16(ldf(whh_b, src));
    }
    for (long i = tid0; i < G4; i += stride) {
        const int g = (int)i & 3, u = (int)i >> 2;
        const long src = g * 128 + u;
        g_bias[0][i] = ldf(bih_f, src) + ldf(bhh_f, src);
        g_bias[1][i] = ldf(bih_b, src) + ldf(bhh_b, src);
    }
    for (long i = tid0; i < T_TAG * 256; i += stride) g_wout[i] = ldf(wout, i);
    for (long i = tid0; i < T_TAG * T_TAG; i += stride) g_trans[i] = ldf(trans, i);
    for (long i = tid0; i < T_TAG; i += stride) {
        g_bout[i]  = ldf(bout, i);
        g_start[i] = ldf(startt, i);
        g_end[i]   = ldf(endt, i);
    }
    for (long i = tid0; i < (long)B_SZ * S_LEN; i += stride)
        g_maskf[i] = ldf(mask, i);
}

// -------------------------------------------------------------------------
// Per-VOCAB input projection: pxv[dir][v] = bias + Wih'@emb[v]^T. MFMA
// columns = 16 tokens per block. Grid (313 token-groups, 2 dir).
// -------------------------------------------------------------------------
__global__ __launch_bounds__(512, 2) void pxv_gemm()
{
    const int grp = blockIdx.x, dir = blockIdx.y;
    const int tid  = threadIdx.x;
    const int lane = tid & 63, wv = tid >> 6;
    const int m16  = lane & 15, quad = lane >> 4;

    bf16x8 V[4][4];
    f32x4 bias4[4];
    #pragma unroll
    for (int t = 0; t < 4; t++) {
        const int np = (wv * 4 + t) * 16 + m16;
        #pragma unroll
        for (int kk = 0; kk < 4; kk++)
            V[t][kk] = *(const bf16x8*)&g_wih[dir][(long)np * E_DIM + kk * 32 + quad * 8];
        const int u = 16 * wv + 4 * t + quad;
        const float4 b4 = *(const float4*)&g_bias[dir][4 * u];
        bias4[t] = (f32x4){b4.x, b4.y, b4.z, b4.w};
    }
    const int v  = grp * 16 + m16;
    const int vv = (v < VOCAB) ? v : 0;
    bf16x8 E[4];
    #pragma unroll
    for (int kk = 0; kk < 4; kk++)
        E[kk] = *(const bf16x8*)&g_emb[(long)vv * E_DIM + kk * 32 + quad * 8];
    #pragma unroll
    for (int t = 0; t < 4; t++) {
        f32x4 px = bias4[t];
        #pragma unroll
        for (int kk = 0; kk < 4; kk++)
            px = __builtin_amdgcn_mfma_f32_16x16x32_bf16(V[t][kk], E[kk], px, 0, 0, 0);
        const int u = 16 * wv + 4 * t + quad;
        if (v < VOCAB)
            *(f32x4*)&g_pxv[((long)(dir * VOCABP + v) * 128 + u) * 4] = px;
    }
}

// -------------------------------------------------------------------------
// Recurrence MFMA scan (R5 structure) + FUSED EMISSION, time-index FIXED:
// at iteration itv the Hh_/Hl_ fragments hold h from step sev-step (they are
// the INPUT to this step's recurrence), so the emission partial computed from
// them is stored via a LAGGING pointer empq (one step behind), guarded for
// itv==0 (zero initial state -> no position). The final step's h is emitted
// in an epilogue after the loop (hB parity 0, visible after the last bar).
// Waves 0-3 each compute one cross term of (WoutHi+WoutLo)@(Hh+Hl) reusing
// the in-register B operands — 4 extra MFMAs/wave/step. Viterbi sums planes.
// Recurrent-path accumulation order identical to R5 — h bit-exact.
// -------------------------------------------------------------------------
#define SCAN_STEP(RD, PX)                                                      \
  {                                                                            \
    const int wr_ = (RD) ^ 1;                                                  \
    /* early: offset+address for the step+2 gather (latency hides below) */    \
    int se2_ = sev + 2 * step;                                                 \
    se2_ = se2_ < 0 ? 0 : (se2_ > S_LEN - 1 ? S_LEN - 1 : se2_);               \
    const float* pf_ = pxvL + xO[se2_ * 16 + m16];                             \
    bf16x8 Hh_[4], Hl_[4];                                                     \
    _Pragma("unroll")                                                          \
    for (int kk = 0; kk < 4; kk++) {                                           \
        const int off_ = ((kk * 4 + quad) * 16 + m16) * 8;                     \
        Hh_[kk] = *(const bf16x8*)&hB[RD][0][off_];                            \
        Hl_[kk] = *(const bf16x8*)&hB[RD][1][off_];                            \
    }                                                                          \
    _Pragma("unroll")                                                          \
    for (int t = 0; t < 4; t++) {                                              \
        _Pragma("unroll")                                                      \
        for (int kk = 0; kk < 4; kk++) {                                       \
            PX[t] = __builtin_amdgcn_mfma_f32_16x16x32_bf16(W[t][kk], Hh_[kk], PX[t], 0, 0, 0); \
            PX[t] = __builtin_amdgcn_mfma_f32_16x16x32_bf16(W[t][kk], Hl_[kk], PX[t], 0, 0, 0); \
        }                                                                      \
    }                                                                          \
    /* fused emission partial from h(prev step) -> LAGGED position empq */     \
    if (wv < 4 && itv) {                                                       \
        f32x4 em_ = {0.f, 0.f, 0.f, 0.f};                                      \
        _Pragma("unroll")                                                      \
        for (int kk = 0; kk < 4; kk++)                                         \
            em_ = __builtin_amdgcn_mfma_f32_16x16x32_bf16(                     \
                WA[kk], (wv & 1) ? Hl_[kk] : Hh_[kk], em_, 0, 0, 0);           \
        empq[0]  = em_[0];                                                     \
        empq[16] = em_[1];                                                     \
        empq[32] = em_[2];                                                     \
        empq[48] = em_[3];                                                     \
    }                                                                          \
    _Pragma("unroll")                                                          \
    for (int t = 0; t < 4; t++) {                                              \
        const float iv = fsig(PX[t][0]);                                       \
        const float fv = fsig(PX[t][1]);                                       \
        const float gv = ftanh(PX[t][2]);                                      \
        const float ov = fsig(PX[t][3]);                                       \
        c[t] = fv * c[t] + iv * gv;                                            \
        const float h = ov * ftanh(c[t]);                                      \
        const int u = 16 * wv + 4 * t + quad;                                  \
        const unsigned ub = __float_as_uint(h);                                \
        const unsigned hb_ = ub >> 16;                                         \
        const float hif = __uint_as_float(ub & 0xFFFF0000u);                   \
        const unsigned lb_ = __float_as_uint(h - hif) >> 16;                   \
        const int ha = (u >> 3) * 128 + m16 * 8 + (u & 7);                     \
        hB[wr_][0][ha] = (unsigned short)hb_;                                  \
        hB[wr_][1][ha] = (unsigned short)lb_;                                  \
    }                                                                          \
    {   /* gather PX for step itv+2 — address precomputed at step top */       \
        PX[0] = *(const f32x4*)(pf_ + 0);                                      \
        PX[1] = *(const f32x4*)(pf_ + 16);                                     \
        PX[2] = *(const f32x4*)(pf_ + 32);                                     \
        PX[3] = *(const f32x4*)(pf_ + 48);                                     \
    }                                                                          \
    asm volatile("s_waitcnt lgkmcnt(0)" ::: "memory");                         \
    __builtin_amdgcn_sched_barrier(0);                                         \
    __builtin_amdgcn_s_barrier();                                              \
    __builtin_amdgcn_sched_barrier(0);                                         \
    empq = empp; empp += empd; sev += step; itv++;                             \
  }

__global__ __launch_bounds__(512, 2) void scan_mfma(const int* __restrict__ x)
{
    __shared__ __align__(16) unsigned short hB[2][2][16 * 16 * 8];  // 16 KB
    __shared__ int xO[S_LEN * 16];   // token * 512 (pxv element offset), 32 KB

    const int bg = blockIdx.x, dir = blockIdx.y;
    const int tid  = threadIdx.x;
    const int lane = tid & 63, wv = tid >> 6;        // wv 0..7
    const int m16  = lane & 15, quad = lane >> 4;

    // persistent A fragments: Whh' rows (4 tiles of 16 rows per wave)
    bf16x8 W[4][4];
    #pragma unroll
    for (int t = 0; t < 4; t++) {
        const int np = (wv * 4 + t) * 16 + m16;
        #pragma unroll
        for (int kk = 0; kk < 4; kk++)
            W[t][kk] = *(const bf16x8*)&g_whh2[dir][(long)np * HHID + kk * 32 + quad * 8];
    }
    // Wout A-fragments for the fused emission (waves 0-3 only): A row = m16
    // (tag j, zero-padded j>=9), k = kk*32+quad*8+elem — identical k mapping
    // to the recurrent fragments. wv 0,1 hold the hi-split, wv 2,3 the lo.
    bf16x8 WA[4];
    if (wv < 4) {
        #pragma unroll
        for (int kk = 0; kk < 4; kk++) {
            #pragma unroll
            for (int j = 0; j < 8; j++) {
                const float w = (m16 < T_TAG)
                    ? g_wout[m16 * 256 + dir * 128 + kk * 32 + quad * 8 + j] : 0.f;
                const unsigned uw  = __float_as_uint(w);
                const unsigned hib = uw >> 16;
                const float hif    = __uint_as_float(uw & 0xFFFF0000u);
                const unsigned lob = __float_as_uint(w - hif) >> 16;
                WA[kk][j] = (short)((wv < 2) ? hib : lob);
            }
        }
    }
    {   // stage token offsets: xO[s*16+m] = x[bg*16+m][s] * 512
        const bool x64 = ((x[1] | x[3] | x[5] | x[7]) == 0);
        for (int i = tid; i < S_LEN * 16; i += 512) {
            const int s = i >> 4, m = i & 15;
            const int ii = (bg * 16 + m) * S_LEN + s;
            int tok = x64 ? x[2 * ii] : x[ii];
            tok = (unsigned)tok < VOCAB ? tok : 0;
            xO[i] = tok * 512;
        }
    }
    for (int i = tid; i < 2 * 2 * 2048; i += 512) ((unsigned short*)hB)[i] = 0;
    float c[4] = {0.f, 0.f, 0.f, 0.f};
    __syncthreads();

    const int se0  = dir ? (S_LEN - 1) : 0;
    const int step = dir ? -1 : 1;
    const int u0   = 16 * wv + quad;

    // pxv lane base: element ((dir*VOCABP + v)*128 + u)*4; v enters via xO
    const float* pxvL = &g_pxv[(long)dir * VOCABP * 512 + u0 * 4];

    f32x4 pxA[4], pxB[4];
    {
        const int o0 = xO[se0 * 16 + m16];
        #pragma unroll
        for (int t = 0; t < 4; t++) pxA[t] = *(const f32x4*)(pxvL + o0 + 16 * t);
        const int se1 = (S_LEN > 1) ? se0 + step : se0;
        const int o1 = xO[se1 * 16 + m16];
        #pragma unroll
        for (int t = 0; t < 4; t++) pxB[t] = *(const f32x4*)(pxvL + o1 + 16 * t);
    }

    // emission-partial store: plane dir*4+wv, element (s*16+bg)*256 +
    // (quad*4+reg)*16 + m16; per-step delta = step*4096 floats.
    // empp = current-step position; empq lags one step (the h actually
    // emitted at iteration itv is h from step sev-step).
    float* empp = &g_emp[dir * 4 + (wv & 3)]
                        [((long)(se0 * 16 + bg)) * 256 + (quad * 4) * 16 + m16];
    const long empd = (long)step * 4096;
    float* empq = empp;

    int itv = 0, sev = se0;

    for (int it = 0; it < S_LEN; it += 2) {
        SCAN_STEP(0, pxA)      // even step: read hB[0], write hB[1]
        SCAN_STEP(1, pxB)      // odd step:  read hB[1], write hB[0]
    }

    // epilogue: emit the FINAL step's h (in hB[0] after the last iteration;
    // visible after the loop's terminal barrier). empq now points at the
    // last position (se0 + 511*step).
    if (wv < 4) {
        bf16x8 Hh_[4], Hl_[4];
        #pragma unroll
        for (int kk = 0; kk < 4; kk++) {
            const int off_ = ((kk * 4 + quad) * 16 + m16) * 8;
            Hh_[kk] = *(const bf16x8*)&hB[0][0][off_];
            Hl_[kk] = *(const bf16x8*)&hB[0][1][off_];
        }
        f32x4 em_ = {0.f, 0.f, 0.f, 0.f};
        #pragma unroll
        for (int kk = 0; kk < 4; kk++)
            em_ = __builtin_amdgcn_mfma_f32_16x16x32_bf16(
                WA[kk], (wv & 1) ? Hl_[kk] : Hh_[kk], em_, 0, 0, 0);
        empq[0]  = em_[0];
        empq[16] = em_[1];
        empq[32] = em_[2];
        empq[48] = em_[3];
    }
}

// -------------------------------------------------------------------------
// Viterbi: 1 wave per block (grid 256, 1 block/CU). Lanes 0..8 = tags,
// score broadcast via wave shfl. Emission reconstructed as the sum of the
// scan's 8 partial planes + bout, scrub0'd — strict first-max semantics.
// -------------------------------------------------------------------------
__global__ __launch_bounds__(64, 1)
void viterbi_kernel(float* __restrict__ out, int out_size)
{
    __shared__ unsigned char bp[S_LEN][T_TAG];
    const int lane = threadIdx.x;
    const int b  = blockIdx.x;
    const int jj = (lane < T_TAG) ? lane : 0;
    const int bg = b >> 4, mm = b & 15;

    float tcol[T_TAG];
    #pragma unroll
    for (int i = 0; i < T_TAG; i++) tcol[i] = g_trans[i * T_TAG + jj];
    const float boj = g_bout[jj];

    float score[T_TAG];
    {
        const float m0 = g_maskf[b * S_LEN + 0];
        #pragma unroll
        for (int i = 0; i < T_TAG; i++) {
            const long o = (long)bg * 256 + i * 16 + mm;
            const float s8 = (((g_emp[0][o] + g_emp[1][o]) + (g_emp[2][o] + g_emp[3][o]))
                            + ((g_emp[4][o] + g_emp[5][o]) + (g_emp[6][o] + g_emp[7][o])));
            score[i] = g_start[i] + scrub0(g_bout[i] + s8) * m0;
        }
    }
    long off = 4096L + (long)bg * 256 + jj * 16 + mm;   // s = 1
    float p0 = g_emp[0][off], p1 = g_emp[1][off], p2 = g_emp[2][off], p3 = g_emp[3][off];
    float p4 = g_emp[4][off], p5 = g_emp[5][off], p6 = g_emp[6][off], p7 = g_emp[7][off];
    float m = g_maskf[b * S_LEN + 1];

    for (int s = 1; s < S_LEN; s++) {
        const long offn = off + 4096;
        float q0 = 0.f, q1 = 0.f, q2 = 0.f, q3 = 0.f;
        float q4 = 0.f, q5 = 0.f, q6 = 0.f, q7 = 0.f, mn = 0.f;
        if (s + 1 < S_LEN) {   // prefetch next step
            q0 = g_emp[0][offn]; q1 = g_emp[1][offn];
            q2 = g_emp[2][offn]; q3 = g_emp[3][offn];
            q4 = g_emp[4][offn]; q5 = g_emp[5][offn];
            q6 = g_emp[6][offn]; q7 = g_emp[7][offn];
            mn = g_maskf[b * S_LEN + s + 1];
        }
        const float e = scrub0(boj + (((p0 + p1) + (p2 + p3)) + ((p4 + p5) + (p6 + p7))));
        float best = score[0] + tcol[0];
        int arg = 0;
        #pragma unroll
        for (int i = 1; i < T_TAG; i++) {
            const float cnd = score[i] + tcol[i];
            if (cnd > best) { best = cnd; arg = i; }
        }
        float ns; int nbp;
        if (m > 0.f) { ns = best + e * m; nbp = arg; }
        else         { ns = score[jj];    nbp = jj;  }
        if (lane < T_TAG) bp[s][jj] = (unsigned char)nbp;
        #pragma unroll
        for (int i = 0; i < T_TAG; i++) score[i] = __shfl(ns, i, 64);
        p0 = q0; p1 = q1; p2 = q2; p3 = q3;
        p4 = q4; p5 = q5; p6 = q6; p7 = q7;
        m = mn; off = offn;
    }
    #pragma unroll
    for (int i = 0; i < T_TAG; i++) score[i] += g_end[i];

    __syncthreads();   // bp visible for backtrace

    if (lane == 0) {
        float bs = score[0]; int last = 0;
        #pragma unroll
        for (int i = 1; i < T_TAG; i++)
            if (score[i] > bs) { bs = score[i]; last = i; }
        {
            const unsigned u = __float_as_uint(bs);
            if (((u >> 23) & 0xFFu) == 0xFFu) bs = -100.f;
        }
        if ((long)B_SZ * S_LEN + b < out_size)
            out[(long)B_SZ * S_LEN + b] = bs;
        int tag = last;
        if (tag < 0) tag = 0; if (tag > 8) tag = 8;
        out[(long)b * S_LEN + (S_LEN - 1)] = (float)tag;
        for (int s2 = S_LEN - 1; s2 >= 1; s2--) {
            tag = bp[s2][tag];
            if (tag < 0) tag = 0; if (tag > 8) tag = 8;
            out[(long)b * S_LEN + (s2 - 1)] = (float)tag;
        }
    }
}

// -------------------------------------------------------------------------
extern "C" void kernel_launch(void* const* d_in, const int* in_sizes, int n_in,
                              void* d_out, int out_size, void* d_ws, size_t ws_size,
                              hipStream_t stream) {
    const int* x = (const int*)d_in[0];
    float* out = (float*)d_out;

    convert_kernel<<<512, 256, 0, stream>>>(
        d_in[1], d_in[2], d_in[3], d_in[4], d_in[5], d_in[6],
        d_in[7], d_in[8], d_in[9], d_in[10], d_in[11], d_in[12],
        d_in[13], d_in[14], d_in[15], out, out_size);
    pxv_gemm<<<dim3((VOCABP / 16), 2), 512, 0, stream>>>();
    scan_mfma<<<dim3(16, 2), 512, 0, stream>>>(x);
    viterbi_kernel<<<256, 64, 0, stream>>>(out, out_size);
}

// Round 11
// 922.184 us; speedup vs baseline: 1.7941x; 1.0102x over previous
//
#include <hip/hip_runtime.h>
#include <hip/hip_bf16.h>
#include <math.h>

#define S_LEN 512
#define B_SZ  256
#define E_DIM 128
#define HHID  128
#define G4    512   // 4*HH
#define T_TAG 9
#define VOCAB 5001
#define VOCABP 5008   // padded to 16 for pxv tiling
#define EMP_SZ (512L * 16 * 256)   // emission positions (s,bg,16j,16m)

typedef __attribute__((ext_vector_type(8))) short bf16x8;
typedef __attribute__((ext_vector_type(4))) float f32x4;
typedef __attribute__((ext_vector_type(8))) unsigned short u16x8;

__device__ __forceinline__ float bf2f(__hip_bfloat16 v) { return __bfloat162float(v); }
__device__ __forceinline__ float scrub0(float v) {       // inf/nan -> 0
    unsigned u = __float_as_uint(v);
    return (((u >> 23) & 0xFFu) == 0xFFu) ? 0.f : v;
}
__device__ __forceinline__ float frcp(float x) { return __builtin_amdgcn_rcpf(x); }
__device__ __forceinline__ float fsig(float x) { return frcp(1.f + __expf(-x)); }
__device__ __forceinline__ float ftanh(float x) {
    return 1.f - 2.f * frcp(1.f + __expf(2.f * x));
}

// ---- .bss scratch ----
__device__ __hip_bfloat16 g_emb[VOCAB * E_DIM];
__device__ __hip_bfloat16 g_wih[2][G4 * E_DIM];    // rows permuted: n' = 4u+g
__device__ __hip_bfloat16 g_whh2[2][G4 * HHID];    // rows permuted: n' = 4u+g
__device__ __align__(16) float g_bias[2][G4];      // permuted
__device__ float g_wout[T_TAG * 256];
__device__ float g_bout[T_TAG];
__device__ float g_trans[T_TAG * T_TAG];
__device__ float g_start[T_TAG];
__device__ float g_end[T_TAG];
__device__ float g_maskf[B_SZ * S_LEN];
// pxv[dir][v][u][g] = bias + Wih'@emb[v] for every VOCAB token (20.5 MB,
// L3-resident). Scan gathers by token id.
__device__ __align__(16) float g_pxv[(long)2 * VOCABP * 128 * 4];
// Fused-emission partials, INTERLEAVED per dir: [dir][pos*4 + part] where
// pos = (s*16+bg)*256 + j*16 + m, part = wave's cross term. One pos = 16
// contiguous bytes -> viterbi reads ONE dwordx4 per dir per step.
__device__ __align__(16) float g_emp[2][EMP_SZ * 4];   // 67 MB

// -------------------------------------------------------------------------
// Canonicalize inputs (bf16/fp32 autodetect via mask). Gate permutation:
// row n' = 4u+g  <->  original torch gate row g*128+u.
// Also zero-fills the output buffer (folded fill_out).
// -------------------------------------------------------------------------
__global__ __launch_bounds__(256) void convert_kernel(
    const void* mask, const void* emb,
    const void* wih_f, const void* whh_f, const void* bih_f, const void* bhh_f,
    const void* wih_b, const void* whh_b, const void* bih_b, const void* bhh_b,
    const void* wout, const void* bout, const void* trans,
    const void* startt, const void* endt, float* out, int out_size)
{
    const bool isb = (((const unsigned*)mask)[0] == 0x3F803F80u);
    auto ldf = [&](const void* p, long i) -> float {
        float v = isb ? bf2f(((const __hip_bfloat16*)p)[i]) : ((const float*)p)[i];
        return scrub0(v);
    };
    const long tid0   = (long)blockIdx.x * blockDim.x + threadIdx.x;
    const long stride = (long)gridDim.x * blockDim.x;

    for (long i = tid0; i < out_size; i += stride) out[i] = 0.f;

    // embedding: vectorized 8-wide (VOCAB*E_DIM = 640128, divisible by 8)
    if (isb) {
        const u16x8* src = (const u16x8*)emb;
        u16x8* dst = (u16x8*)g_emb;
        for (long i = tid0; i < (long)VOCAB * E_DIM / 8; i += stride) {
            u16x8 v = src[i];
            #pragma unroll
            for (int j = 0; j < 8; j++)
                if (((v[j] >> 7) & 0xFFu) == 0xFFu) v[j] = 0;
            dst[i] = v;
        }
    } else {
        const float4* src = (const float4*)emb;
        for (long i = tid0; i < (long)VOCAB * E_DIM / 4; i += stride) {
            const float4 v = src[i];
            __hip_bfloat16* d = &g_emb[i * 4];
            d[0] = __float2bfloat16(scrub0(v.x));
            d[1] = __float2bfloat16(scrub0(v.y));
            d[2] = __float2bfloat16(scrub0(v.z));
            d[3] = __float2bfloat16(scrub0(v.w));
        }
    }
    for (long i = tid0; i < (long)G4 * E_DIM; i += stride) {
        const int np = (int)(i >> 7), e = (int)(i & 127);
        const int g = np & 3, u = np >> 2;
        const long src = (long)(g * 128 + u) * E_DIM + e;
        g_wih[0][i] = __float2bfloat16(ldf(wih_f, src));
        g_wih[1][i] = __float2bfloat16(ldf(wih_b, src));
    }
    for (long i = tid0; i < (long)G4 * HHID; i += stride) {
        const int np = (int)(i >> 7), k = (int)(i & 127);
        const int g = np & 3, u = np >> 2;
        const long src = (long)(g * 128 + u) * HHID + k;
        g_whh2[0][i] = __float2bfloat16(ldf(whh_f, src));
        g_whh2[1][i] = __float2bfloat16(ldf(whh_b, src));
    }
    for (long i = tid0; i < G4; i += stride) {
        const int g = (int)i & 3, u = (int)i >> 2;
        const long src = g * 128 + u;
        g_bias[0][i] = ldf(bih_f, src) + ldf(bhh_f, src);
        g_bias[1][i] = ldf(bih_b, src) + ldf(bhh_b, src);
    }
    for (long i = tid0; i < T_TAG * 256; i += stride) g_wout[i] = ldf(wout, i);
    for (long i = tid0; i < T_TAG * T_TAG; i += stride) g_trans[i] = ldf(trans, i);
    for (long i = tid0; i < T_TAG; i += stride) {
        g_bout[i]  = ldf(bout, i);
        g_start[i] = ldf(startt, i);
        g_end[i]   = ldf(endt, i);
    }
    for (long i = tid0; i < (long)B_SZ * S_LEN; i += stride)
        g_maskf[i] = ldf(mask, i);
}

// -------------------------------------------------------------------------
// Per-VOCAB input projection: pxv[dir][v] = bias + Wih'@emb[v]^T. MFMA
// columns = 16 tokens per block. Grid (313 token-groups, 2 dir).
// -------------------------------------------------------------------------
__global__ __launch_bounds__(512, 2) void pxv_gemm()
{
    const int grp = blockIdx.x, dir = blockIdx.y;
    const int tid  = threadIdx.x;
    const int lane = tid & 63, wv = tid >> 6;
    const int m16  = lane & 15, quad = lane >> 4;

    bf16x8 V[4][4];
    f32x4 bias4[4];
    #pragma unroll
    for (int t = 0; t < 4; t++) {
        const int np = (wv * 4 + t) * 16 + m16;
        #pragma unroll
        for (int kk = 0; kk < 4; kk++)
            V[t][kk] = *(const bf16x8*)&g_wih[dir][(long)np * E_DIM + kk * 32 + quad * 8];
        const int u = 16 * wv + 4 * t + quad;
        const float4 b4 = *(const float4*)&g_bias[dir][4 * u];
        bias4[t] = (f32x4){b4.x, b4.y, b4.z, b4.w};
    }
    const int v  = grp * 16 + m16;
    const int vv = (v < VOCAB) ? v : 0;
    bf16x8 E[4];
    #pragma unroll
    for (int kk = 0; kk < 4; kk++)
        E[kk] = *(const bf16x8*)&g_emb[(long)vv * E_DIM + kk * 32 + quad * 8];
    #pragma unroll
    for (int t = 0; t < 4; t++) {
        f32x4 px = bias4[t];
        #pragma unroll
        for (int kk = 0; kk < 4; kk++)
            px = __builtin_amdgcn_mfma_f32_16x16x32_bf16(V[t][kk], E[kk], px, 0, 0, 0);
        const int u = 16 * wv + 4 * t + quad;
        if (v < VOCAB)
            *(f32x4*)&g_pxv[((long)(dir * VOCABP + v) * 128 + u) * 4] = px;
    }
}

// -------------------------------------------------------------------------
// Recurrence MFMA scan (R5 structure) + fused emission (R10, lagged store).
// R11: emission partials stored into the INTERLEAVED layout — element
// (pos*4 + wv), pos = (s*16+bg)*256 + quad*64 + reg*16 + m16. The 4 waves
// of one block fill each 16-byte group within one step (same L2, good
// combining); viterbi then reads one dwordx4 per dir per step.
// Recurrent-path accumulation order identical to R5 — h bit-exact.
// -------------------------------------------------------------------------
#define SCAN_STEP(RD, PX)                                                      \
  {                                                                            \
    const int wr_ = (RD) ^ 1;                                                  \
    /* early: offset+address for the step+2 gather (latency hides below) */    \
    int se2_ = sev + 2 * step;                                                 \
    se2_ = se2_ < 0 ? 0 : (se2_ > S_LEN - 1 ? S_LEN - 1 : se2_);               \
    const float* pf_ = pxvL + xO[se2_ * 16 + m16];                             \
    bf16x8 Hh_[4], Hl_[4];                                                     \
    _Pragma("unroll")                                                          \
    for (int kk = 0; kk < 4; kk++) {                                           \
        const int off_ = ((kk * 4 + quad) * 16 + m16) * 8;                     \
        Hh_[kk] = *(const bf16x8*)&hB[RD][0][off_];                            \
        Hl_[kk] = *(const bf16x8*)&hB[RD][1][off_];                            \
    }                                                                          \
    _Pragma("unroll")                                                          \
    for (int t = 0; t < 4; t++) {                                              \
        _Pragma("unroll")                                                      \
        for (int kk = 0; kk < 4; kk++) {                                       \
            PX[t] = __builtin_amdgcn_mfma_f32_16x16x32_bf16(W[t][kk], Hh_[kk], PX[t], 0, 0, 0); \
            PX[t] = __builtin_amdgcn_mfma_f32_16x16x32_bf16(W[t][kk], Hl_[kk], PX[t], 0, 0, 0); \
        }                                                                      \
    }                                                                          \
    /* fused emission partial from h(prev step) -> LAGGED position empq */     \
    if (wv < 4 && itv) {                                                       \
        f32x4 em_ = {0.f, 0.f, 0.f, 0.f};                                      \
        _Pragma("unroll")                                                      \
        for (int kk = 0; kk < 4; kk++)                                         \
            em_ = __builtin_amdgcn_mfma_f32_16x16x32_bf16(                     \
                WA[kk], (wv & 1) ? Hl_[kk] : Hh_[kk], em_, 0, 0, 0);           \
        empq[0]   = em_[0];                                                    \
        empq[64]  = em_[1];                                                    \
        empq[128] = em_[2];                                                    \
        empq[192] = em_[3];                                                    \
    }                                                                          \
    _Pragma("unroll")                                                          \
    for (int t = 0; t < 4; t++) {                                              \
        const float iv = fsig(PX[t][0]);                                       \
        const float fv = fsig(PX[t][1]);                                       \
        const float gv = ftanh(PX[t][2]);                                      \
        const float ov = fsig(PX[t][3]);                                       \
        c[t] = fv * c[t] + iv * gv;                                            \
        const float h = ov * ftanh(c[t]);                                      \
        const int u = 16 * wv + 4 * t + quad;                                  \
        const unsigned ub = __float_as_uint(h);                                \
        const unsigned hb_ = ub >> 16;                                         \
        const float hif = __uint_as_float(ub & 0xFFFF0000u);                   \
        const unsigned lb_ = __float_as_uint(h - hif) >> 16;                   \
        const int ha = (u >> 3) * 128 + m16 * 8 + (u & 7);                     \
        hB[wr_][0][ha] = (unsigned short)hb_;                                  \
        hB[wr_][1][ha] = (unsigned short)lb_;                                  \
    }                                                                          \
    {   /* gather PX for step itv+2 — address precomputed at step top */       \
        PX[0] = *(const f32x4*)(pf_ + 0);                                      \
        PX[1] = *(const f32x4*)(pf_ + 16);                                     \
        PX[2] = *(const f32x4*)(pf_ + 32);                                     \
        PX[3] = *(const f32x4*)(pf_ + 48);                                     \
    }                                                                          \
    asm volatile("s_waitcnt lgkmcnt(0)" ::: "memory");                         \
    __builtin_amdgcn_sched_barrier(0);                                         \
    __builtin_amdgcn_s_barrier();                                              \
    __builtin_amdgcn_sched_barrier(0);                                         \
    empq = empp; empp += empd; sev += step; itv++;                             \
  }

__global__ __launch_bounds__(512, 2) void scan_mfma(const int* __restrict__ x)
{
    __shared__ __align__(16) unsigned short hB[2][2][16 * 16 * 8];  // 16 KB
    __shared__ int xO[S_LEN * 16];   // token * 512 (pxv element offset), 32 KB

    const int bg = blockIdx.x, dir = blockIdx.y;
    const int tid  = threadIdx.x;
    const int lane = tid & 63, wv = tid >> 6;        // wv 0..7
    const int m16  = lane & 15, quad = lane >> 4;

    // persistent A fragments: Whh' rows (4 tiles of 16 rows per wave)
    bf16x8 W[4][4];
    #pragma unroll
    for (int t = 0; t < 4; t++) {
        const int np = (wv * 4 + t) * 16 + m16;
        #pragma unroll
        for (int kk = 0; kk < 4; kk++)
            W[t][kk] = *(const bf16x8*)&g_whh2[dir][(long)np * HHID + kk * 32 + quad * 8];
    }
    // Wout A-fragments for the fused emission (waves 0-3 only): A row = m16
    // (tag j, zero-padded j>=9), k = kk*32+quad*8+elem — identical k mapping
    // to the recurrent fragments. wv 0,1 hold the hi-split, wv 2,3 the lo.
    bf16x8 WA[4];
    if (wv < 4) {
        #pragma unroll
        for (int kk = 0; kk < 4; kk++) {
            #pragma unroll
            for (int j = 0; j < 8; j++) {
                const float w = (m16 < T_TAG)
                    ? g_wout[m16 * 256 + dir * 128 + kk * 32 + quad * 8 + j] : 0.f;
                const unsigned uw  = __float_as_uint(w);
                const unsigned hib = uw >> 16;
                const float hif    = __uint_as_float(uw & 0xFFFF0000u);
                const unsigned lob = __float_as_uint(w - hif) >> 16;
                WA[kk][j] = (short)((wv < 2) ? hib : lob);
            }
        }
    }
    {   // stage token offsets: xO[s*16+m] = x[bg*16+m][s] * 512
        const bool x64 = ((x[1] | x[3] | x[5] | x[7]) == 0);
        for (int i = tid; i < S_LEN * 16; i += 512) {
            const int s = i >> 4, m = i & 15;
            const int ii = (bg * 16 + m) * S_LEN + s;
            int tok = x64 ? x[2 * ii] : x[ii];
            tok = (unsigned)tok < VOCAB ? tok : 0;
            xO[i] = tok * 512;
        }
    }
    for (int i = tid; i < 2 * 2 * 2048; i += 512) ((unsigned short*)hB)[i] = 0;
    float c[4] = {0.f, 0.f, 0.f, 0.f};
    __syncthreads();

    const int se0  = dir ? (S_LEN - 1) : 0;
    const int step = dir ? -1 : 1;
    const int u0   = 16 * wv + quad;

    // pxv lane base: element ((dir*VOCABP + v)*128 + u)*4; v enters via xO
    const float* pxvL = &g_pxv[(long)dir * VOCABP * 512 + u0 * 4];

    f32x4 pxA[4], pxB[4];
    {
        const int o0 = xO[se0 * 16 + m16];
        #pragma unroll
        for (int t = 0; t < 4; t++) pxA[t] = *(const f32x4*)(pxvL + o0 + 16 * t);
        const int se1 = (S_LEN > 1) ? se0 + step : se0;
        const int o1 = xO[se1 * 16 + m16];
        #pragma unroll
        for (int t = 0; t < 4; t++) pxB[t] = *(const f32x4*)(pxvL + o1 + 16 * t);
    }

    // emission-partial store (interleaved layout): element = pos*4 + wv,
    // pos = (se*16+bg)*256 + quad*64 + reg*16 + m16; per-step Δ = step*16384.
    // empq lags one step (the h emitted at iteration itv is from sev-step).
    float* empp = &g_emp[dir]
        [(((long)(se0 * 16 + bg) * 256 + quad * 64 + m16) << 2) + (wv & 3)];
    const long empd = (long)step * 16384;
    float* empq = empp;

    int itv = 0, sev = se0;

    for (int it = 0; it < S_LEN; it += 2) {
        SCAN_STEP(0, pxA)      // even step: read hB[0], write hB[1]
        SCAN_STEP(1, pxB)      // odd step:  read hB[1], write hB[0]
    }

    // epilogue: emit the FINAL step's h (in hB[0] after the last iteration;
    // visible after the loop's terminal barrier). empq points at the last
    // position (se0 + 511*step).
    if (wv < 4) {
        bf16x8 Hh_[4], Hl_[4];
        #pragma unroll
        for (int kk = 0; kk < 4; kk++) {
            const int off_ = ((kk * 4 + quad) * 16 + m16) * 8;
            Hh_[kk] = *(const bf16x8*)&hB[0][0][off_];
            Hl_[kk] = *(const bf16x8*)&hB[0][1][off_];
        }
        f32x4 em_ = {0.f, 0.f, 0.f, 0.f};
        #pragma unroll
        for (int kk = 0; kk < 4; kk++)
            em_ = __builtin_amdgcn_mfma_f32_16x16x32_bf16(
                WA[kk], (wv & 1) ? Hl_[kk] : Hh_[kk], em_, 0, 0, 0);
        empq[0]   = em_[0];
        empq[64]  = em_[1];
        empq[128] = em_[2];
        empq[192] = em_[3];
    }
}

// -------------------------------------------------------------------------
// Viterbi: 1 wave per block (grid 256, 1 block/CU). Lanes 0..8 = tags.
// R11: emission = 2 dwordx4 loads (interleaved partials), prefetched TWO
// steps ahead (named register sets, unroll-2) — covers the ~300-500 cy
// L2/L3 latency that the old 1-step / 8-scalar-load scheme exposed.
// Partial summation order identical to R10 — scores bit-identical.
// -------------------------------------------------------------------------
#define VLOAD(S, A, C, M)                                                      \
  {                                                                            \
    const long e_ = ((long)((S) * 16 + bg) * 256 + jj * 16 + mm) << 2;         \
    A = *(const f32x4*)&g_emp[0][e_];                                          \
    C = *(const f32x4*)&g_emp[1][e_];                                          \
    M = g_maskf[b * S_LEN + (S)];                                              \
  }

#define VSTEP(S, A, C, M)                                                      \
  {                                                                            \
    const float e = scrub0(boj + (((A[0] + A[1]) + (A[2] + A[3]))              \
                                + ((C[0] + C[1]) + (C[2] + C[3]))));           \
    float best = score[0] + tcol[0];                                           \
    int arg = 0;                                                               \
    _Pragma("unroll")                                                          \
    for (int i = 1; i < T_TAG; i++) {                                          \
        const float cnd = score[i] + tcol[i];                                  \
        if (cnd > best) { best = cnd; arg = i; }                               \
    }                                                                          \
    float ns; int nbp;                                                         \
    if (M > 0.f) { ns = best + e * M; nbp = arg; }                             \
    else         { ns = score[jj];    nbp = jj;  }                             \
    if (lane < T_TAG) bp[S][jj] = (unsigned char)nbp;                          \
    _Pragma("unroll")                                                          \
    for (int i = 0; i < T_TAG; i++) score[i] = __shfl(ns, i, 64);              \
  }

__global__ __launch_bounds__(64, 1)
void viterbi_kernel(float* __restrict__ out, int out_size)
{
    __shared__ unsigned char bp[S_LEN][T_TAG];
    const int lane = threadIdx.x;
    const int b  = blockIdx.x;
    const int jj = (lane < T_TAG) ? lane : 0;
    const int bg = b >> 4, mm = b & 15;

    float tcol[T_TAG];
    #pragma unroll
    for (int i = 0; i < T_TAG; i++) tcol[i] = g_trans[i * T_TAG + jj];
    const float boj = g_bout[jj];

    float score[T_TAG];
    {
        const float m0 = g_maskf[b * S_LEN + 0];
        #pragma unroll
        for (int i = 0; i < T_TAG; i++) {
            const long o = ((long)bg * 256 + i * 16 + mm) << 2;
            const f32x4 A = *(const f32x4*)&g_emp[0][o];
            const f32x4 C = *(const f32x4*)&g_emp[1][o];
            const float s8 = (((A[0] + A[1]) + (A[2] + A[3]))
                            + ((C[0] + C[1]) + (C[2] + C[3])));
            score[i] = g_start[i] + scrub0(g_bout[i] + s8) * m0;
        }
    }

    f32x4 a0, c0, a1, c1, a2, c2, a3, c3;
    float m0_, m1_, m2_, m3_;
    VLOAD(1, a0, c0, m0_)
    VLOAD(2, a1, c1, m1_)

    for (int s = 1; s < S_LEN; s += 2) {
        const int s2 = (s + 2 < S_LEN) ? s + 2 : s;
        VLOAD(s2, a2, c2, m2_)
        VSTEP(s, a0, c0, m0_)
        const int s3 = (s + 3 < S_LEN) ? s + 3 : s;
        VLOAD(s3, a3, c3, m3_)
        if (s + 1 < S_LEN) VSTEP(s + 1, a1, c1, m1_)
        a0 = a2; c0 = c2; m0_ = m2_;
        a1 = a3; c1 = c3; m1_ = m3_;
    }
    #pragma unroll
    for (int i = 0; i < T_TAG; i++) score[i] += g_end[i];

    __syncthreads();   // bp visible for backtrace

    if (lane == 0) {
        float bs = score[0]; int last = 0;
        #pragma unroll
        for (int i = 1; i < T_TAG; i++)
            if (score[i] > bs) { bs = score[i]; last = i; }
        {
            const unsigned u = __float_as_uint(bs);
            if (((u >> 23) & 0xFFu) == 0xFFu) bs = -100.f;
        }
        if ((long)B_SZ * S_LEN + b < out_size)
            out[(long)B_SZ * S_LEN + b] = bs;
        int tag = last;
        if (tag < 0) tag = 0; if (tag > 8) tag = 8;
        out[(long)b * S_LEN + (S_LEN - 1)] = (float)tag;
        for (int s2 = S_LEN - 1; s2 >= 1; s2--) {
            tag = bp[s2][tag];
            if (tag < 0) tag = 0; if (tag > 8) tag = 8;
            out[(long)b * S_LEN + (s2 - 1)] = (float)tag;
        }
    }
}

// -------------------------------------------------------------------------
extern "C" void kernel_launch(void* const* d_in, const int* in_sizes, int n_in,
                              void* d_out, int out_size, void* d_ws, size_t ws_size,
                              hipStream_t stream) {
    const int* x = (const int*)d_in[0];
    float* out = (float*)d_out;

    convert_kernel<<<512, 256, 0, stream>>>(
        d_in[1], d_in[2], d_in[3], d_in[4], d_in[5], d_in[6],
        d_in[7], d_in[8], d_in[9], d_in[10], d_in[11], d_in[12],
        d_in[13], d_in[14], d_in[15], out, out_size);
    pxv_gemm<<<dim3((VOCABP / 16), 2), 512, 0, stream>>>();
    scan_mfma<<<dim3(16, 2), 512, 0, stream>>>(x);
    viterbi_kernel<<<256, 64, 0, stream>>>(out, out_size);
}

// Round 12
// 914.480 us; speedup vs baseline: 1.8092x; 1.0084x over previous
//
#include <hip/hip_runtime.h>
#include <hip/hip_bf16.h>
#include <math.h>

#define S_LEN 512
#define B_SZ  256
#define E_DIM 128
#define HHID  128
#define G4    512   // 4*HH
#define T_TAG 9
#define VOCAB 5001
#define VOCABP 5008   // padded to 16 for pxv tiling
#define EMP_SZ (512L * 16 * 256)   // per-partial emission plane (s,bg,16j,16m)

typedef __attribute__((ext_vector_type(8))) short bf16x8;
typedef __attribute__((ext_vector_type(4))) float f32x4;
typedef __attribute__((ext_vector_type(8))) unsigned short u16x8;

__device__ __forceinline__ float bf2f(__hip_bfloat16 v) { return __bfloat162float(v); }
__device__ __forceinline__ float scrub0(float v) {       // inf/nan -> 0
    unsigned u = __float_as_uint(v);
    return (((u >> 23) & 0xFFu) == 0xFFu) ? 0.f : v;
}
__device__ __forceinline__ float frcp(float x) { return __builtin_amdgcn_rcpf(x); }
__device__ __forceinline__ float fsig(float x) { return frcp(1.f + __expf(-x)); }
__device__ __forceinline__ float ftanh(float x) {
    return 1.f - 2.f * frcp(1.f + __expf(2.f * x));
}

// ---- .bss scratch ----
__device__ __hip_bfloat16 g_emb[VOCAB * E_DIM];
__device__ __hip_bfloat16 g_wih[2][G4 * E_DIM];    // rows permuted: n' = 4u+g
__device__ __hip_bfloat16 g_whh2[2][G4 * HHID];    // rows permuted: n' = 4u+g
__device__ __align__(16) float g_bias[2][G4];      // permuted
__device__ float g_wout[T_TAG * 256];
__device__ float g_bout[T_TAG];
__device__ float g_trans[T_TAG * T_TAG];
__device__ float g_start[T_TAG];
__device__ float g_end[T_TAG];
__device__ float g_maskf[B_SZ * S_LEN];
// pxv[dir][v][u][g] = bias + Wih'@emb[v] for every VOCAB token (20.5 MB,
// L3-resident). Scan gathers by token id.
__device__ __align__(16) float g_pxv[(long)2 * VOCABP * 128 * 4];
// Fused-emission partials, PLANE-major (R10 layout — scan-side coalesced:
// m16 innermost -> 64B segments): [dir*4 + part][(s*16+bg)*256 + j*16 + m].
// part = cross term {WhiHh, WhiHl, WloHh, WloHl}; viterbi sums the 8 planes.
__device__ __align__(16) float g_emp[8][EMP_SZ];   // 67 MB

// -------------------------------------------------------------------------
// Canonicalize inputs (bf16/fp32 autodetect via mask). Gate permutation:
// row n' = 4u+g  <->  original torch gate row g*128+u.
// Also zero-fills the output buffer (folded fill_out).
// -------------------------------------------------------------------------
__global__ __launch_bounds__(256) void convert_kernel(
    const void* mask, const void* emb,
    const void* wih_f, const void* whh_f, const void* bih_f, const void* bhh_f,
    const void* wih_b, const void* whh_b, const void* bih_b, const void* bhh_b,
    const void* wout, const void* bout, const void* trans,
    const void* startt, const void* endt, float* out, int out_size)
{
    const bool isb = (((const unsigned*)mask)[0] == 0x3F803F80u);
    auto ldf = [&](const void* p, long i) -> float {
        float v = isb ? bf2f(((const __hip_bfloat16*)p)[i]) : ((const float*)p)[i];
        return scrub0(v);
    };
    const long tid0   = (long)blockIdx.x * blockDim.x + threadIdx.x;
    const long stride = (long)gridDim.x * blockDim.x;

    for (long i = tid0; i < out_size; i += stride) out[i] = 0.f;

    // embedding: vectorized 8-wide (VOCAB*E_DIM = 640128, divisible by 8)
    if (isb) {
        const u16x8* src = (const u16x8*)emb;
        u16x8* dst = (u16x8*)g_emb;
        for (long i = tid0; i < (long)VOCAB * E_DIM / 8; i += stride) {
            u16x8 v = src[i];
            #pragma unroll
            for (int j = 0; j < 8; j++)
                if (((v[j] >> 7) & 0xFFu) == 0xFFu) v[j] = 0;
            dst[i] = v;
        }
    } else {
        const float4* src = (const float4*)emb;
        for (long i = tid0; i < (long)VOCAB * E_DIM / 4; i += stride) {
            const float4 v = src[i];
            __hip_bfloat16* d = &g_emb[i * 4];
            d[0] = __float2bfloat16(scrub0(v.x));
            d[1] = __float2bfloat16(scrub0(v.y));
            d[2] = __float2bfloat16(scrub0(v.z));
            d[3] = __float2bfloat16(scrub0(v.w));
        }
    }
    for (long i = tid0; i < (long)G4 * E_DIM; i += stride) {
        const int np = (int)(i >> 7), e = (int)(i & 127);
        const int g = np & 3, u = np >> 2;
        const long src = (long)(g * 128 + u) * E_DIM + e;
        g_wih[0][i] = __float2bfloat16(ldf(wih_f, src));
        g_wih[1][i] = __float2bfloat16(ldf(wih_b, src));
    }
    for (long i = tid0; i < (long)G4 * HHID; i += stride) {
        const int np = (int)(i >> 7), k = (int)(i & 127);
        const int g = np & 3, u = np >> 2;
        const long src = (long)(g * 128 + u) * HHID + k;
        g_whh2[0][i] = __float2bfloat16(ldf(whh_f, src));
        g_whh2[1][i] = __float2bfloat16(ldf(whh_b, src));
    }
    for (long i = tid0; i < G4; i += stride) {
        const int g = (int)i & 3, u = (int)i >> 2;
        const long src = g * 128 + u;
        g_bias[0][i] = ldf(bih_f, src) + ldf(bhh_f, src);
        g_bias[1][i] = ldf(bih_b, src) + ldf(bhh_b, src);
    }
    for (long i = tid0; i < T_TAG * 256; i += stride) g_wout[i] = ldf(wout, i);
    for (long i = tid0; i < T_TAG * T_TAG; i += stride) g_trans[i] = ldf(trans, i);
    for (long i = tid0; i < T_TAG; i += stride) {
        g_bout[i]  = ldf(bout, i);
        g_start[i] = ldf(startt, i);
        g_end[i]   = ldf(endt, i);
    }
    for (long i = tid0; i < (long)B_SZ * S_LEN; i += stride)
        g_maskf[i] = ldf(mask, i);
}

// -------------------------------------------------------------------------
// Per-VOCAB input projection: pxv[dir][v] = bias + Wih'@emb[v]^T. MFMA
// columns = 16 tokens per block. Grid (313 token-groups, 2 dir).
// -------------------------------------------------------------------------
__global__ __launch_bounds__(512, 2) void pxv_gemm()
{
    const int grp = blockIdx.x, dir = blockIdx.y;
    const int tid  = threadIdx.x;
    const int lane = tid & 63, wv = tid >> 6;
    const int m16  = lane & 15, quad = lane >> 4;

    bf16x8 V[4][4];
    f32x4 bias4[4];
    #pragma unroll
    for (int t = 0; t < 4; t++) {
        const int np = (wv * 4 + t) * 16 + m16;
        #pragma unroll
        for (int kk = 0; kk < 4; kk++)
            V[t][kk] = *(const bf16x8*)&g_wih[dir][(long)np * E_DIM + kk * 32 + quad * 8];
        const int u = 16 * wv + 4 * t + quad;
        const float4 b4 = *(const float4*)&g_bias[dir][4 * u];
        bias4[t] = (f32x4){b4.x, b4.y, b4.z, b4.w};
    }
    const int v  = grp * 16 + m16;
    const int vv = (v < VOCAB) ? v : 0;
    bf16x8 E[4];
    #pragma unroll
    for (int kk = 0; kk < 4; kk++)
        E[kk] = *(const bf16x8*)&g_emb[(long)vv * E_DIM + kk * 32 + quad * 8];
    #pragma unroll
    for (int t = 0; t < 4; t++) {
        f32x4 px = bias4[t];
        #pragma unroll
        for (int kk = 0; kk < 4; kk++)
            px = __builtin_amdgcn_mfma_f32_16x16x32_bf16(V[t][kk], E[kk], px, 0, 0, 0);
        const int u = 16 * wv + 4 * t + quad;
        if (v < VOCAB)
            *(f32x4*)&g_pxv[((long)(dir * VOCABP + v) * 128 + u) * 4] = px;
    }
}

// -------------------------------------------------------------------------
// Recurrence MFMA scan (R5 structure) + fused emission (R10: plane-major
// coalesced store, lagged one step, epilogue for the final h).
// Waves 0-3 each compute one cross term of (WoutHi+WoutLo)@(Hh+Hl) reusing
// the in-register B operands — 4 extra MFMAs/wave/step.
// Recurrent-path accumulation order identical to R5 — h bit-exact.
// -------------------------------------------------------------------------
#define SCAN_STEP(RD, PX)                                                      \
  {                                                                            \
    const int wr_ = (RD) ^ 1;                                                  \
    /* early: offset+address for the step+2 gather (latency hides below) */    \
    int se2_ = sev + 2 * step;                                                 \
    se2_ = se2_ < 0 ? 0 : (se2_ > S_LEN - 1 ? S_LEN - 1 : se2_);               \
    const float* pf_ = pxvL + xO[se2_ * 16 + m16];                             \
    bf16x8 Hh_[4], Hl_[4];                                                     \
    _Pragma("unroll")                                                          \
    for (int kk = 0; kk < 4; kk++) {                                           \
        const int off_ = ((kk * 4 + quad) * 16 + m16) * 8;                     \
        Hh_[kk] = *(const bf16x8*)&hB[RD][0][off_];                            \
        Hl_[kk] = *(const bf16x8*)&hB[RD][1][off_];                            \
    }                                                                          \
    _Pragma("unroll")                                                          \
    for (int t = 0; t < 4; t++) {                                              \
        _Pragma("unroll")                                                      \
        for (int kk = 0; kk < 4; kk++) {                                       \
            PX[t] = __builtin_amdgcn_mfma_f32_16x16x32_bf16(W[t][kk], Hh_[kk], PX[t], 0, 0, 0); \
            PX[t] = __builtin_amdgcn_mfma_f32_16x16x32_bf16(W[t][kk], Hl_[kk], PX[t], 0, 0, 0); \
        }                                                                      \
    }                                                                          \
    /* fused emission partial from h(prev step) -> LAGGED position empq */     \
    if (wv < 4 && itv) {                                                       \
        f32x4 em_ = {0.f, 0.f, 0.f, 0.f};                                      \
        _Pragma("unroll")                                                      \
        for (int kk = 0; kk < 4; kk++)                                         \
            em_ = __builtin_amdgcn_mfma_f32_16x16x32_bf16(                     \
                WA[kk], (wv & 1) ? Hl_[kk] : Hh_[kk], em_, 0, 0, 0);           \
        empq[0]  = em_[0];                                                     \
        empq[16] = em_[1];                                                     \
        empq[32] = em_[2];                                                     \
        empq[48] = em_[3];                                                     \
    }                                                                          \
    _Pragma("unroll")                                                          \
    for (int t = 0; t < 4; t++) {                                              \
        const float iv = fsig(PX[t][0]);                                       \
        const float fv = fsig(PX[t][1]);                                       \
        const float gv = ftanh(PX[t][2]);                                      \
        const float ov = fsig(PX[t][3]);                                       \
        c[t] = fv * c[t] + iv * gv;                                            \
        const float h = ov * ftanh(c[t]);                                      \
        const int u = 16 * wv + 4 * t + quad;                                  \
        const unsigned ub = __float_as_uint(h);                                \
        const unsigned hb_ = ub >> 16;                                         \
        const float hif = __uint_as_float(ub & 0xFFFF0000u);                   \
        const unsigned lb_ = __float_as_uint(h - hif) >> 16;                   \
        const int ha = (u >> 3) * 128 + m16 * 8 + (u & 7);                     \
        hB[wr_][0][ha] = (unsigned short)hb_;                                  \
        hB[wr_][1][ha] = (unsigned short)lb_;                                  \
    }                                                                          \
    {   /* gather PX for step itv+2 — address precomputed at step top */       \
        PX[0] = *(const f32x4*)(pf_ + 0);                                      \
        PX[1] = *(const f32x4*)(pf_ + 16);                                     \
        PX[2] = *(const f32x4*)(pf_ + 32);                                     \
        PX[3] = *(const f32x4*)(pf_ + 48);                                     \
    }                                                                          \
    asm volatile("s_waitcnt lgkmcnt(0)" ::: "memory");                         \
    __builtin_amdgcn_sched_barrier(0);                                         \
    __builtin_amdgcn_s_barrier();                                              \
    __builtin_amdgcn_sched_barrier(0);                                         \
    empq = empp; empp += empd; sev += step; itv++;                             \
  }

__global__ __launch_bounds__(512, 2) void scan_mfma(const int* __restrict__ x)
{
    __shared__ __align__(16) unsigned short hB[2][2][16 * 16 * 8];  // 16 KB
    __shared__ int xO[S_LEN * 16];   // token * 512 (pxv element offset), 32 KB

    const int bg = blockIdx.x, dir = blockIdx.y;
    const int tid  = threadIdx.x;
    const int lane = tid & 63, wv = tid >> 6;        // wv 0..7
    const int m16  = lane & 15, quad = lane >> 4;

    // persistent A fragments: Whh' rows (4 tiles of 16 rows per wave)
    bf16x8 W[4][4];
    #pragma unroll
    for (int t = 0; t < 4; t++) {
        const int np = (wv * 4 + t) * 16 + m16;
        #pragma unroll
        for (int kk = 0; kk < 4; kk++)
            W[t][kk] = *(const bf16x8*)&g_whh2[dir][(long)np * HHID + kk * 32 + quad * 8];
    }
    // Wout A-fragments for the fused emission (waves 0-3 only): A row = m16
    // (tag j, zero-padded j>=9), k = kk*32+quad*8+elem — identical k mapping
    // to the recurrent fragments. wv 0,1 hold the hi-split, wv 2,3 the lo.
    bf16x8 WA[4];
    if (wv < 4) {
        #pragma unroll
        for (int kk = 0; kk < 4; kk++) {
            #pragma unroll
            for (int j = 0; j < 8; j++) {
                const float w = (m16 < T_TAG)
                    ? g_wout[m16 * 256 + dir * 128 + kk * 32 + quad * 8 + j] : 0.f;
                const unsigned uw  = __float_as_uint(w);
                const unsigned hib = uw >> 16;
                const float hif    = __uint_as_float(uw & 0xFFFF0000u);
                const unsigned lob = __float_as_uint(w - hif) >> 16;
                WA[kk][j] = (short)((wv < 2) ? hib : lob);
            }
        }
    }
    {   // stage token offsets: xO[s*16+m] = x[bg*16+m][s] * 512
        const bool x64 = ((x[1] | x[3] | x[5] | x[7]) == 0);
        for (int i = tid; i < S_LEN * 16; i += 512) {
            const int s = i >> 4, m = i & 15;
            const int ii = (bg * 16 + m) * S_LEN + s;
            int tok = x64 ? x[2 * ii] : x[ii];
            tok = (unsigned)tok < VOCAB ? tok : 0;
            xO[i] = tok * 512;
        }
    }
    for (int i = tid; i < 2 * 2 * 2048; i += 512) ((unsigned short*)hB)[i] = 0;
    float c[4] = {0.f, 0.f, 0.f, 0.f};
    __syncthreads();

    const int se0  = dir ? (S_LEN - 1) : 0;
    const int step = dir ? -1 : 1;
    const int u0   = 16 * wv + quad;

    // pxv lane base: element ((dir*VOCABP + v)*128 + u)*4; v enters via xO
    const float* pxvL = &g_pxv[(long)dir * VOCABP * 512 + u0 * 4];

    f32x4 pxA[4], pxB[4];
    {
        const int o0 = xO[se0 * 16 + m16];
        #pragma unroll
        for (int t = 0; t < 4; t++) pxA[t] = *(const f32x4*)(pxvL + o0 + 16 * t);
        const int se1 = (S_LEN > 1) ? se0 + step : se0;
        const int o1 = xO[se1 * 16 + m16];
        #pragma unroll
        for (int t = 0; t < 4; t++) pxB[t] = *(const f32x4*)(pxvL + o1 + 16 * t);
    }

    // emission-partial store (plane layout): plane dir*4+wv, element
    // (s*16+bg)*256 + (quad*4+reg)*16 + m16 — m16 innermost => coalesced.
    // empq lags one step (the h emitted at iteration itv is from sev-step).
    float* empp = &g_emp[dir * 4 + (wv & 3)]
                        [((long)(se0 * 16 + bg)) * 256 + (quad * 4) * 16 + m16];
    const long empd = (long)step * 4096;
    float* empq = empp;

    int itv = 0, sev = se0;

    for (int it = 0; it < S_LEN; it += 2) {
        SCAN_STEP(0, pxA)      // even step: read hB[0], write hB[1]
        SCAN_STEP(1, pxB)      // odd step:  read hB[1], write hB[0]
    }

    // epilogue: emit the FINAL step's h (in hB[0] after the last iteration;
    // visible after the loop's terminal barrier). empq points at the last
    // position (se0 + 511*step).
    if (wv < 4) {
        bf16x8 Hh_[4], Hl_[4];
        #pragma unroll
        for (int kk = 0; kk < 4; kk++) {
            const int off_ = ((kk * 4 + quad) * 16 + m16) * 8;
            Hh_[kk] = *(const bf16x8*)&hB[0][0][off_];
            Hl_[kk] = *(const bf16x8*)&hB[0][1][off_];
        }
        f32x4 em_ = {0.f, 0.f, 0.f, 0.f};
        #pragma unroll
        for (int kk = 0; kk < 4; kk++)
            em_ = __builtin_amdgcn_mfma_f32_16x16x32_bf16(
                WA[kk], (wv & 1) ? Hl_[kk] : Hh_[kk], em_, 0, 0, 0);
        empq[0]  = em_[0];
        empq[16] = em_[1];
        empq[32] = em_[2];
        empq[48] = em_[3];
    }
}

// -------------------------------------------------------------------------
// Viterbi: 1 wave per block (grid 256, 1 block/CU). Lanes 0..8 = tags.
// R12: R11's unroll-2 / 2-step-prefetch structure (the −43µs lever) on the
// 8-plane layout — the 8 scalar loads per step issue back-to-back two steps
// (~300+ cy) ahead of use. Partial summation order identical to R10 —
// scores bit-identical.
// -------------------------------------------------------------------------
#define VLOAD(S, P, M)                                                         \
  {                                                                            \
    const long e_ = (long)((S) * 16 + bg) * 256 + jj * 16 + mm;                \
    P[0] = g_emp[0][e_]; P[1] = g_emp[1][e_];                                  \
    P[2] = g_emp[2][e_]; P[3] = g_emp[3][e_];                                  \
    P[4] = g_emp[4][e_]; P[5] = g_emp[5][e_];                                  \
    P[6] = g_emp[6][e_]; P[7] = g_emp[7][e_];                                  \
    M = g_maskf[b * S_LEN + (S)];                                              \
  }

#define VSTEP(S, P, M)                                                         \
  {                                                                            \
    const float e = scrub0(boj + (((P[0] + P[1]) + (P[2] + P[3]))              \
                                + ((P[4] + P[5]) + (P[6] + P[7]))));           \
    float best = score[0] + tcol[0];                                           \
    int arg = 0;                                                               \
    _Pragma("unroll")                                                          \
    for (int i = 1; i < T_TAG; i++) {                                          \
        const float cnd = score[i] + tcol[i];                                  \
        if (cnd > best) { best = cnd; arg = i; }                               \
    }                                                                          \
    float ns; int nbp;                                                         \
    if (M > 0.f) { ns = best + e * M; nbp = arg; }                             \
    else         { ns = score[jj];    nbp = jj;  }                             \
    if (lane < T_TAG) bp[S][jj] = (unsigned char)nbp;                          \
    _Pragma("unroll")                                                          \
    for (int i = 0; i < T_TAG; i++) score[i] = __shfl(ns, i, 64);              \
  }

__global__ __launch_bounds__(64, 1)
void viterbi_kernel(float* __restrict__ out, int out_size)
{
    __shared__ unsigned char bp[S_LEN][T_TAG];
    const int lane = threadIdx.x;
    const int b  = blockIdx.x;
    const int jj = (lane < T_TAG) ? lane : 0;
    const int bg = b >> 4, mm = b & 15;

    float tcol[T_TAG];
    #pragma unroll
    for (int i = 0; i < T_TAG; i++) tcol[i] = g_trans[i * T_TAG + jj];
    const float boj = g_bout[jj];

    float score[T_TAG];
    {
        const float m0 = g_maskf[b * S_LEN + 0];
        #pragma unroll
        for (int i = 0; i < T_TAG; i++) {
            const long o = (long)bg * 256 + i * 16 + mm;
            const float s8 = (((g_emp[0][o] + g_emp[1][o]) + (g_emp[2][o] + g_emp[3][o]))
                            + ((g_emp[4][o] + g_emp[5][o]) + (g_emp[6][o] + g_emp[7][o])));
            score[i] = g_start[i] + scrub0(g_bout[i] + s8) * m0;
        }
    }

    float pA[8], pB[8], pC[8], pD[8];
    float mA, mB, mC, mD;
    VLOAD(1, pA, mA)
    VLOAD(2, pB, mB)

    for (int s = 1; s < S_LEN; s += 2) {
        const int s2 = (s + 2 < S_LEN) ? s + 2 : s;
        VLOAD(s2, pC, mC)
        VSTEP(s, pA, mA)
        const int s3 = (s + 3 < S_LEN) ? s + 3 : s;
        VLOAD(s3, pD, mD)
        if (s + 1 < S_LEN) VSTEP(s + 1, pB, mB)
        #pragma unroll
        for (int i = 0; i < 8; i++) { pA[i] = pC[i]; pB[i] = pD[i]; }
        mA = mC; mB = mD;
    }
    #pragma unroll
    for (int i = 0; i < T_TAG; i++) score[i] += g_end[i];

    __syncthreads();   // bp visible for backtrace

    if (lane == 0) {
        float bs = score[0]; int last = 0;
        #pragma unroll
        for (int i = 1; i < T_TAG; i++)
            if (score[i] > bs) { bs = score[i]; last = i; }
        {
            const unsigned u = __float_as_uint(bs);
            if (((u >> 23) & 0xFFu) == 0xFFu) bs = -100.f;
        }
        if ((long)B_SZ * S_LEN + b < out_size)
            out[(long)B_SZ * S_LEN + b] = bs;
        int tag = last;
        if (tag < 0) tag = 0; if (tag > 8) tag = 8;
        out[(long)b * S_LEN + (S_LEN - 1)] = (float)tag;
        for (int s2 = S_LEN - 1; s2 >= 1; s2--) {
            tag = bp[s2][tag];
            if (tag < 0) tag = 0; if (tag > 8) tag = 8;
            out[(long)b * S_LEN + (s2 - 1)] = (float)tag;
        }
    }
}

// -------------------------------------------------------------------------
extern "C" void kernel_launch(void* const* d_in, const int* in_sizes, int n_in,
                              void* d_out, int out_size, void* d_ws, size_t ws_size,
                              hipStream_t stream) {
    const int* x = (const int*)d_in[0];
    float* out = (float*)d_out;

    convert_kernel<<<512, 256, 0, stream>>>(
        d_in[1], d_in[2], d_in[3], d_in[4], d_in[5], d_in[6],
        d_in[7], d_in[8], d_in[9], d_in[10], d_in[11], d_in[12],
        d_in[13], d_in[14], d_in[15], out, out_size);
    pxv_gemm<<<dim3((VOCABP / 16), 2), 512, 0, stream>>>();
    scan_mfma<<<dim3(16, 2), 512, 0, stream>>>(x);
    viterbi_kernel<<<256, 64, 0, stream>>>(out, out_size);
}

// Round 14
// 892.409 us; speedup vs baseline: 1.8540x; 1.0247x over previous
//
#include <hip/hip_runtime.h>
#include <hip/hip_bf16.h>
#include <math.h>

#define S_LEN 512
#define B_SZ  256
#define E_DIM 128
#define HHID  128
#define G4    512   // 4*HH
#define T_TAG 9
#define VOCAB 5001
#define VOCABP 5008   // padded to 16 for pxv tiling
#define EMP_SZ (512L * 16 * 256)   // emission positions (s,bg,16j,16m)

typedef __attribute__((ext_vector_type(8))) short bf16x8;
typedef __attribute__((ext_vector_type(4))) float f32x4;
typedef __attribute__((ext_vector_type(8))) unsigned short u16x8;

__device__ __forceinline__ float bf2f(__hip_bfloat16 v) { return __bfloat162float(v); }
__device__ __forceinline__ float scrub0(float v) {       // inf/nan -> 0
    unsigned u = __float_as_uint(v);
    return (((u >> 23) & 0xFFu) == 0xFFu) ? 0.f : v;
}
__device__ __forceinline__ float frcp(float x) { return __builtin_amdgcn_rcpf(x); }
__device__ __forceinline__ float fsig(float x) { return frcp(1.f + __expf(-x)); }
__device__ __forceinline__ float ftanh(float x) {
    return 1.f - 2.f * frcp(1.f + __expf(2.f * x));
}

// ---- .bss scratch ----
__device__ __hip_bfloat16 g_emb[VOCAB * E_DIM];
__device__ __hip_bfloat16 g_wih[2][G4 * E_DIM];    // rows permuted: n' = 4u+g
__device__ __hip_bfloat16 g_whh2[2][G4 * HHID];    // rows permuted: n' = 4u+g
__device__ __align__(16) float g_bias[2][G4];      // permuted
__device__ float g_wout[T_TAG * 256];
__device__ float g_bout[T_TAG];
__device__ float g_trans[T_TAG * T_TAG];
__device__ float g_start[T_TAG];
__device__ float g_end[T_TAG];
__device__ float g_maskf[B_SZ * S_LEN];
// pxv[dir][v][u][g] = bias + Wih'@emb[v] for every VOCAB token (20.5 MB,
// L3-resident). Scan gathers by token id.
__device__ __align__(16) float g_pxv[(long)2 * VOCABP * 128 * 4];
// Fused-emission partials, INTERLEAVED (R11 viterbi-friendly layout):
// [dir][(s*16+bg)*1024 + (j*16+m)*4 + part]. Scan writes them COALESCED via
// an LDS combine (emL) — each step's 4KB block streamed out as dwordx2.
__device__ __align__(16) float g_emi[2][EMP_SZ * 4];   // 67 MB

// -------------------------------------------------------------------------
// Canonicalize inputs (bf16/fp32 autodetect via mask). Gate permutation:
// row n' = 4u+g  <->  original torch gate row g*128+u.
// Also zero-fills the output buffer (folded fill_out).
// -------------------------------------------------------------------------
__global__ __launch_bounds__(256) void convert_kernel(
    const void* mask, const void* emb,
    const void* wih_f, const void* whh_f, const void* bih_f, const void* bhh_f,
    const void* wih_b, const void* whh_b, const void* bih_b, const void* bhh_b,
    const void* wout, const void* bout, const void* trans,
    const void* startt, const void* endt, float* out, int out_size)
{
    const bool isb = (((const unsigned*)mask)[0] == 0x3F803F80u);
    auto ldf = [&](const void* p, long i) -> float {
        float v = isb ? bf2f(((const __hip_bfloat16*)p)[i]) : ((const float*)p)[i];
        return scrub0(v);
    };
    const long tid0   = (long)blockIdx.x * blockDim.x + threadIdx.x;
    const long stride = (long)gridDim.x * blockDim.x;

    for (long i = tid0; i < out_size; i += stride) out[i] = 0.f;

    // embedding: vectorized 8-wide (VOCAB*E_DIM = 640128, divisible by 8)
    if (isb) {
        const u16x8* src = (const u16x8*)emb;
        u16x8* dst = (u16x8*)g_emb;
        for (long i = tid0; i < (long)VOCAB * E_DIM / 8; i += stride) {
            u16x8 v = src[i];
            #pragma unroll
            for (int j = 0; j < 8; j++)
                if (((v[j] >> 7) & 0xFFu) == 0xFFu) v[j] = 0;
            dst[i] = v;
        }
    } else {
        const float4* src = (const float4*)emb;
        for (long i = tid0; i < (long)VOCAB * E_DIM / 4; i += stride) {
            const float4 v = src[i];
            __hip_bfloat16* d = &g_emb[i * 4];
            d[0] = __float2bfloat16(scrub0(v.x));
            d[1] = __float2bfloat16(scrub0(v.y));
            d[2] = __float2bfloat16(scrub0(v.z));
            d[3] = __float2bfloat16(scrub0(v.w));
        }
    }
    for (long i = tid0; i < (long)G4 * E_DIM; i += stride) {
        const int np = (int)(i >> 7), e = (int)(i & 127);
        const int g = np & 3, u = np >> 2;
        const long src = (long)(g * 128 + u) * E_DIM + e;
        g_wih[0][i] = __float2bfloat16(ldf(wih_f, src));
        g_wih[1][i] = __float2bfloat16(ldf(wih_b, src));
    }
    for (long i = tid0; i < (long)G4 * HHID; i += stride) {
        const int np = (int)(i >> 7), k = (int)(i & 127);
        const int g = np & 3, u = np >> 2;
        const long src = (long)(g * 128 + u) * HHID + k;
        g_whh2[0][i] = __float2bfloat16(ldf(whh_f, src));
        g_whh2[1][i] = __float2bfloat16(ldf(whh_b, src));
    }
    for (long i = tid0; i < G4; i += stride) {
        const int g = (int)i & 3, u = (int)i >> 2;
        const long src = g * 128 + u;
        g_bias[0][i] = ldf(bih_f, src) + ldf(bhh_f, src);
        g_bias[1][i] = ldf(bih_b, src) + ldf(bhh_b, src);
    }
    for (long i = tid0; i < T_TAG * 256; i += stride) g_wout[i] = ldf(wout, i);
    for (long i = tid0; i < T_TAG * T_TAG; i += stride) g_trans[i] = ldf(trans, i);
    for (long i = tid0; i < T_TAG; i += stride) {
        g_bout[i]  = ldf(bout, i);
        g_start[i] = ldf(startt, i);
        g_end[i]   = ldf(endt, i);
    }
    for (long i = tid0; i < (long)B_SZ * S_LEN; i += stride)
        g_maskf[i] = ldf(mask, i);
}

// -------------------------------------------------------------------------
// Per-VOCAB input projection: pxv[dir][v] = bias + Wih'@emb[v]^T. MFMA
// columns = 16 tokens per block. Grid (313 token-groups, 2 dir).
// -------------------------------------------------------------------------
__global__ __launch_bounds__(512, 2) void pxv_gemm()
{
    const int grp = blockIdx.x, dir = blockIdx.y;
    const int tid  = threadIdx.x;
    const int lane = tid & 63, wv = tid >> 6;
    const int m16  = lane & 15, quad = lane >> 4;

    bf16x8 V[4][4];
    f32x4 bias4[4];
    #pragma unroll
    for (int t = 0; t < 4; t++) {
        const int np = (wv * 4 + t) * 16 + m16;
        #pragma unroll
        for (int kk = 0; kk < 4; kk++)
            V[t][kk] = *(const bf16x8*)&g_wih[dir][(long)np * E_DIM + kk * 32 + quad * 8];
        const int u = 16 * wv + 4 * t + quad;
        const float4 b4 = *(const float4*)&g_bias[dir][4 * u];
        bias4[t] = (f32x4){b4.x, b4.y, b4.z, b4.w};
    }
    const int v  = grp * 16 + m16;
    const int vv = (v < VOCAB) ? v : 0;
    bf16x8 E[4];
    #pragma unroll
    for (int kk = 0; kk < 4; kk++)
        E[kk] = *(const bf16x8*)&g_emb[(long)vv * E_DIM + kk * 32 + quad * 8];
    #pragma unroll
    for (int t = 0; t < 4; t++) {
        f32x4 px = bias4[t];
        #pragma unroll
        for (int kk = 0; kk < 4; kk++)
            px = __builtin_amdgcn_mfma_f32_16x16x32_bf16(V[t][kk], E[kk], px, 0, 0, 0);
        const int u = 16 * wv + 4 * t + quad;
        if (v < VOCAB)
            *(f32x4*)&g_pxv[((long)(dir * VOCABP + v) * 128 + u) * 4] = px;
    }
}

// -------------------------------------------------------------------------
// Recurrence MFMA scan (R5 structure) + fused emission with LDS COMBINE:
// waves 0-3 ds_write their cross-term partials into emL[step&1] (8KB parity
// buffer); after the step barrier (visibility via the existing lgkmcnt(0))
// ALL 8 waves stream the combined 4KB block out as coalesced dwordx2 into
// the interleaved g_emi layout. Write-out lags TWO steps (emg2<-emg1<-emg0);
// epilogue flushes positions 510 and 511. Same partials + same viterbi sum
// order as R11 -> scores bit-identical. Recurrent path identical to R5.
// -------------------------------------------------------------------------
#define SCAN_STEP(RD, PX)                                                      \
  {                                                                            \
    const int wr_ = (RD) ^ 1;                                                  \
    /* write-out of step itv-2's combined partials (written to emL[RD^1]) */   \
    if (itv >= 2) {                                                            \
        const float2 wo_ = *(const float2*)&emL[(RD) ^ 1][tid * 2];            \
        *(float2*)emg2 = wo_;                                                  \
    }                                                                          \
    /* early: offset+address for the step+2 gather (latency hides below) */    \
    int se2_ = sev + 2 * step;                                                 \
    se2_ = se2_ < 0 ? 0 : (se2_ > S_LEN - 1 ? S_LEN - 1 : se2_);               \
    const float* pf_ = pxvL + xO[se2_ * 16 + m16];                             \
    bf16x8 Hh_[4], Hl_[4];                                                     \
    _Pragma("unroll")                                                          \
    for (int kk = 0; kk < 4; kk++) {                                           \
        const int off_ = ((kk * 4 + quad) * 16 + m16) * 8;                     \
        Hh_[kk] = *(const bf16x8*)&hB[RD][0][off_];                            \
        Hl_[kk] = *(const bf16x8*)&hB[RD][1][off_];                            \
    }                                                                          \
    _Pragma("unroll")                                                          \
    for (int t = 0; t < 4; t++) {                                              \
        _Pragma("unroll")                                                      \
        for (int kk = 0; kk < 4; kk++) {                                       \
            PX[t] = __builtin_amdgcn_mfma_f32_16x16x32_bf16(W[t][kk], Hh_[kk], PX[t], 0, 0, 0); \
            PX[t] = __builtin_amdgcn_mfma_f32_16x16x32_bf16(W[t][kk], Hl_[kk], PX[t], 0, 0, 0); \
        }                                                                      \
    }                                                                          \
    /* fused emission partial from h(prev step) -> emL[RD] (combine buffer) */ \
    if (wv < 4 && itv) {                                                       \
        f32x4 em_ = {0.f, 0.f, 0.f, 0.f};                                      \
        _Pragma("unroll")                                                      \
        for (int kk = 0; kk < 4; kk++)                                         \
            em_ = __builtin_amdgcn_mfma_f32_16x16x32_bf16(                     \
                WA[kk], (wv & 1) ? Hl_[kk] : Hh_[kk], em_, 0, 0, 0);           \
        emL[RD][ebase]       = em_[0];                                         \
        emL[RD][ebase + 64]  = em_[1];                                         \
        emL[RD][ebase + 128] = em_[2];                                         \
        emL[RD][ebase + 192] = em_[3];                                         \
    }                                                                          \
    _Pragma("unroll")                                                          \
    for (int t = 0; t < 4; t++) {                                              \
        const float iv = fsig(PX[t][0]);                                       \
        const float fv = fsig(PX[t][1]);                                       \
        const float gv = ftanh(PX[t][2]);                                      \
        const float ov = fsig(PX[t][3]);                                       \
        c[t] = fv * c[t] + iv * gv;                                            \
        const float h = ov * ftanh(c[t]);                                      \
        const int u = 16 * wv + 4 * t + quad;                                  \
        const unsigned ub = __float_as_uint(h);                                \
        const unsigned hb_ = ub >> 16;                                         \
        const float hif = __uint_as_float(ub & 0xFFFF0000u);                   \
        const unsigned lb_ = __float_as_uint(h - hif) >> 16;                   \
        const int ha = (u >> 3) * 128 + m16 * 8 + (u & 7);                     \
        hB[wr_][0][ha] = (unsigned short)hb_;                                  \
        hB[wr_][1][ha] = (unsigned short)lb_;                                  \
    }                                                                          \
    {   /* gather PX for step itv+2 — address precomputed at step top */       \
        PX[0] = *(const f32x4*)(pf_ + 0);                                      \
        PX[1] = *(const f32x4*)(pf_ + 16);                                     \
        PX[2] = *(const f32x4*)(pf_ + 32);                                     \
        PX[3] = *(const f32x4*)(pf_ + 48);                                     \
    }                                                                          \
    asm volatile("s_waitcnt lgkmcnt(0)" ::: "memory");                         \
    __builtin_amdgcn_sched_barrier(0);                                         \
    __builtin_amdgcn_s_barrier();                                              \
    __builtin_amdgcn_sched_barrier(0);                                         \
    emg2 = emg1; emg1 = emg0; emg0 += emgd;                                    \
    sev += step; itv++;                                                        \
  }

__global__ __launch_bounds__(512, 2) void scan_mfma(const int* __restrict__ x)
{
    __shared__ __align__(16) unsigned short hB[2][2][16 * 16 * 8];  // 16 KB
    __shared__ int xO[S_LEN * 16];   // token * 512 (pxv element offset), 32 KB
    __shared__ __align__(16) float emL[2][1024];   // 8 KB emission combine

    const int bg = blockIdx.x, dir = blockIdx.y;
    const int tid  = threadIdx.x;
    const int lane = tid & 63, wv = tid >> 6;        // wv 0..7
    const int m16  = lane & 15, quad = lane >> 4;
    const int ebase = quad * 256 + m16 * 4 + (wv & 3);   // emL write base

    // persistent A fragments: Whh' rows (4 tiles of 16 rows per wave)
    bf16x8 W[4][4];
    #pragma unroll
    for (int t = 0; t < 4; t++) {
        const int np = (wv * 4 + t) * 16 + m16;
        #pragma unroll
        for (int kk = 0; kk < 4; kk++)
            W[t][kk] = *(const bf16x8*)&g_whh2[dir][(long)np * HHID + kk * 32 + quad * 8];
    }
    // Wout A-fragments for the fused emission (waves 0-3 only): A row = m16
    // (tag j, zero-padded j>=9), k = kk*32+quad*8+elem — identical k mapping
    // to the recurrent fragments. wv 0,1 hold the hi-split, wv 2,3 the lo.
    bf16x8 WA[4];
    if (wv < 4) {
        #pragma unroll
        for (int kk = 0; kk < 4; kk++) {
            #pragma unroll
            for (int j = 0; j < 8; j++) {
                const float w = (m16 < T_TAG)
                    ? g_wout[m16 * 256 + dir * 128 + kk * 32 + quad * 8 + j] : 0.f;
                const unsigned uw  = __float_as_uint(w);
                const unsigned hib = uw >> 16;
                const float hif    = __uint_as_float(uw & 0xFFFF0000u);
                const unsigned lob = __float_as_uint(w - hif) >> 16;
                WA[kk][j] = (short)((wv < 2) ? hib : lob);
            }
        }
    }
    {   // stage token offsets: xO[s*16+m] = x[bg*16+m][s] * 512
        const bool x64 = ((x[1] | x[3] | x[5] | x[7]) == 0);
        for (int i = tid; i < S_LEN * 16; i += 512) {
            const int s = i >> 4, m = i & 15;
            const int ii = (bg * 16 + m) * S_LEN + s;
            int tok = x64 ? x[2 * ii] : x[ii];
            tok = (unsigned)tok < VOCAB ? tok : 0;
            xO[i] = tok * 512;
        }
    }
    for (int i = tid; i < 2 * 2 * 2048; i += 512) ((unsigned short*)hB)[i] = 0;
    float c[4] = {0.f, 0.f, 0.f, 0.f};
    __syncthreads();

    const int se0  = dir ? (S_LEN - 1) : 0;
    const int step = dir ? -1 : 1;
    const int u0   = 16 * wv + quad;

    // pxv lane base: element ((dir*VOCABP + v)*128 + u)*4; v enters via xO
    const float* pxvL = &g_pxv[(long)dir * VOCABP * 512 + u0 * 4];

    f32x4 pxA[4], pxB[4];
    {
        const int o0 = xO[se0 * 16 + m16];
        #pragma unroll
        for (int t = 0; t < 4; t++) pxA[t] = *(const f32x4*)(pxvL + o0 + 16 * t);
        const int se1 = (S_LEN > 1) ? se0 + step : se0;
        const int o1 = xO[se1 * 16 + m16];
        #pragma unroll
        for (int t = 0; t < 4; t++) pxB[t] = *(const f32x4*)(pxvL + o1 + 16 * t);
    }

    // emission write-out pointers (2-step lag): block base for step s is
    // g_emi[dir] + (s*16+bg)*1024; each thread streams 2 floats (dwordx2).
    float* emg0 = &g_emi[dir][((long)(se0 * 16 + bg)) * 1024 + tid * 2];
    const long emgd = (long)step * 16384;
    float* emg1 = emg0;
    float* emg2 = emg0;

    int itv = 0, sev = se0;

    for (int it = 0; it < S_LEN; it += 2) {
        SCAN_STEP(0, pxA)      // even step: read hB[0], write hB[1]
        SCAN_STEP(1, pxB)      // odd step:  read hB[1], write hB[0]
    }

    // epilogue A: flush position 510 — its combined partials sit in emL[1]
    // (written at itv=511), visible after the loop's terminal barrier.
    {
        const float2 wo_ = *(const float2*)&emL[1][tid * 2];
        *(float2*)emg2 = wo_;     // emg2 == base(pos 510)
    }
    // epilogue B: emit the FINAL step's h (in hB[0]) -> emL[0] -> pos 511.
    if (wv < 4) {
        bf16x8 Hh_[4], Hl_[4];
        #pragma unroll
        for (int kk = 0; kk < 4; kk++) {
            const int off_ = ((kk * 4 + quad) * 16 + m16) * 8;
            Hh_[kk] = *(const bf16x8*)&hB[0][0][off_];
            Hl_[kk] = *(const bf16x8*)&hB[0][1][off_];
        }
        f32x4 em_ = {0.f, 0.f, 0.f, 0.f};
        #pragma unroll
        for (int kk = 0; kk < 4; kk++)
            em_ = __builtin_amdgcn_mfma_f32_16x16x32_bf16(
                WA[kk], (wv & 1) ? Hl_[kk] : Hh_[kk], em_, 0, 0, 0);
        emL[0][ebase]       = em_[0];
        emL[0][ebase + 64]  = em_[1];
        emL[0][ebase + 128] = em_[2];
        emL[0][ebase + 192] = em_[3];
    }
    asm volatile("s_waitcnt lgkmcnt(0)" ::: "memory");
    __builtin_amdgcn_sched_barrier(0);
    __builtin_amdgcn_s_barrier();
    __builtin_amdgcn_sched_barrier(0);
    {
        const float2 wo_ = *(const float2*)&emL[0][tid * 2];
        *(float2*)emg1 = wo_;     // emg1 == base(pos 511)
    }
}

// -------------------------------------------------------------------------
// Viterbi (R11 structure): 1 wave per block (grid 256). Lanes 0..8 = tags.
// Emission = 2 dwordx4 loads (interleaved partials), prefetched TWO steps
// ahead. Partial summation order identical to R11/R12 — scores bit-identical.
// -------------------------------------------------------------------------
#define VLOAD(S, A, C, M)                                                      \
  {                                                                            \
    const long e_ = ((long)((S) * 16 + bg) * 256 + jj * 16 + mm) << 2;         \
    A = *(const f32x4*)&g_emi[0][e_];                                          \
    C = *(const f32x4*)&g_emi[1][e_];                                          \
    M = g_maskf[b * S_LEN + (S)];                                              \
  }

#define VSTEP(S, A, C, M)                                                      \
  {                                                                            \
    const float e = scrub0(boj + (((A[0] + A[1]) + (A[2] + A[3]))              \
                                + ((C[0] + C[1]) + (C[2] + C[3]))));           \
    float best = score[0] + tcol[0];                                           \
    int arg = 0;                                                               \
    _Pragma("unroll")                                                          \
    for (int i = 1; i < T_TAG; i++) {                                          \
        const float cnd = score[i] + tcol[i];                                  \
        if (cnd > best) { best = cnd; arg = i; }                               \
    }                                                                          \
    float ns; int nbp;                                                         \
    if (M > 0.f) { ns = best + e * M; nbp = arg; }                             \
    else         { ns = score[jj];    nbp = jj;  }                             \
    if (lane < T_TAG) bp[S][jj] = (unsigned char)nbp;                          \
    _Pragma("unroll")                                                          \
    for (int i = 0; i < T_TAG; i++) score[i] = __shfl(ns, i, 64);              \
  }

__global__ __launch_bounds__(64, 1)
void viterbi_kernel(float* __restrict__ out, int out_size)
{
    __shared__ unsigned char bp[S_LEN][T_TAG];
    const int lane = threadIdx.x;
    const int b  = blockIdx.x;
    const int jj = (lane < T_TAG) ? lane : 0;
    const int bg = b >> 4, mm = b & 15;

    float tcol[T_TAG];
    #pragma unroll
    for (int i = 0; i < T_TAG; i++) tcol[i] = g_trans[i * T_TAG + jj];
    const float boj = g_bout[jj];

    float score[T_TAG];
    {
        const float m0 = g_maskf[b * S_LEN + 0];
        #pragma unroll
        for (int i = 0; i < T_TAG; i++) {
            const long o = ((long)bg * 256 + i * 16 + mm) << 2;
            const f32x4 A = *(const f32x4*)&g_emi[0][o];
            const f32x4 C = *(const f32x4*)&g_emi[1][o];
            const float s8 = (((A[0] + A[1]) + (A[2] + A[3]))
                            + ((C[0] + C[1]) + (C[2] + C[3])));
            score[i] = g_start[i] + scrub0(g_bout[i] + s8) * m0;
        }
    }

    f32x4 a0, c0, a1, c1, a2, c2, a3, c3;
    float m0_, m1_, m2_, m3_;
    VLOAD(1, a0, c0, m0_)
    VLOAD(2, a1, c1, m1_)

    for (int s = 1; s < S_LEN; s += 2) {
        const int s2 = (s + 2 < S_LEN) ? s + 2 : s;
        VLOAD(s2, a2, c2, m2_)
        VSTEP(s, a0, c0, m0_)
        const int s3 = (s + 3 < S_LEN) ? s + 3 : s;
        VLOAD(s3, a3, c3, m3_)
        if (s + 1 < S_LEN) VSTEP(s + 1, a1, c1, m1_)
        a0 = a2; c0 = c2; m0_ = m2_;
        a1 = a3; c1 = c3; m1_ = m3_;
    }
    #pragma unroll
    for (int i = 0; i < T_TAG; i++) score[i] += g_end[i];

    __syncthreads();   // bp visible for backtrace

    if (lane == 0) {
        float bs = score[0]; int last = 0;
        #pragma unroll
        for (int i = 1; i < T_TAG; i++)
            if (score[i] > bs) { bs = score[i]; last = i; }
        {
            const unsigned u = __float_as_uint(bs);
            if (((u >> 23) & 0xFFu) == 0xFFu) bs = -100.f;
        }
        if ((long)B_SZ * S_LEN + b < out_size)
            out[(long)B_SZ * S_LEN + b] = bs;
        int tag = last;
        if (tag < 0) tag = 0; if (tag > 8) tag = 8;
        out[(long)b * S_LEN + (S_LEN - 1)] = (float)tag;
        for (int s2 = S_LEN - 1; s2 >= 1; s2--) {
            tag = bp[s2][tag];
            if (tag < 0) tag = 0; if (tag > 8) tag = 8;
            out[(long)b * S_LEN + (s2 - 1)] = (float)tag;
        }
    }
}

// -------------------------------------------------------------------------
extern "C" void kernel_launch(void* const* d_in, const int* in_sizes, int n_in,
                              void* d_out, int out_size, void* d_ws, size_t ws_size,
                              hipStream_t stream) {
    const int* x = (const int*)d_in[0];
    float* out = (float*)d_out;

    convert_kernel<<<512, 256, 0, stream>>>(
        d_in[1], d_in[2], d_in[3], d_in[4], d_in[5], d_in[6],
        d_in[7], d_in[8], d_in[9], d_in[10], d_in[11], d_in[12],
        d_in[13], d_in[14], d_in[15], out, out_size);
    pxv_gemm<<<dim3((VOCABP / 16), 2), 512, 0, stream>>>();
    scan_mfma<<<dim3(16, 2), 512, 0, stream>>>(x);
    viterbi_kernel<<<256, 64, 0, stream>>>(out, out_size);
}

// Round 15
// 878.459 us; speedup vs baseline: 1.8834x; 1.0159x over previous
//
#include <hip/hip_runtime.h>
#include <hip/hip_bf16.h>
#include <math.h>

#define S_LEN 512
#define B_SZ  256
#define E_DIM 128
#define HHID  128
#define G4    512   // 4*HH
#define T_TAG 9
#define VOCAB 5001
#define VOCABP 5008   // padded to 16 for pxv tiling
#define EMP_SZ (512L * 16 * 256)   // emission positions (s,bg,16j,16m)

typedef __attribute__((ext_vector_type(8))) short bf16x8;
typedef __attribute__((ext_vector_type(4))) float f32x4;
typedef __attribute__((ext_vector_type(8))) unsigned short u16x8;

__device__ __forceinline__ float bf2f(__hip_bfloat16 v) { return __bfloat162float(v); }
__device__ __forceinline__ float scrub0(float v) {       // inf/nan -> 0
    unsigned u = __float_as_uint(v);
    return (((u >> 23) & 0xFFu) == 0xFFu) ? 0.f : v;
}
__device__ __forceinline__ float frcp(float x) { return __builtin_amdgcn_rcpf(x); }
__device__ __forceinline__ float fsig(float x) { return frcp(1.f + __expf(-x)); }
__device__ __forceinline__ float ftanh(float x) {
    return 1.f - 2.f * frcp(1.f + __expf(2.f * x));
}

// ---- .bss scratch ----
__device__ __hip_bfloat16 g_emb[VOCAB * E_DIM];
__device__ __hip_bfloat16 g_wih[2][G4 * E_DIM];    // rows permuted: n' = 4u+g
__device__ __hip_bfloat16 g_whh2[2][G4 * HHID];    // rows permuted: n' = 4u+g
__device__ __align__(16) float g_bias[2][G4];      // permuted
__device__ float g_wout[T_TAG * 256];
__device__ float g_bout[T_TAG];
__device__ float g_trans[T_TAG * T_TAG];
__device__ float g_start[T_TAG];
__device__ float g_end[T_TAG];
__device__ float g_maskf[B_SZ * S_LEN];
// pxv[dir][v][u][g] = bias + Wih'@emb[v] for every VOCAB token (20.5 MB,
// L3-resident). Scan gathers by token id.
__device__ __align__(16) float g_pxv[(long)2 * VOCABP * 128 * 4];
// Fused-emission partials, INTERLEAVED (R11 viterbi-friendly layout):
// [dir][(s*16+bg)*1024 + (j*16+m)*4 + part]. Scan writes them COALESCED via
// an LDS combine (emL) — each step's 4KB block streamed out as dwordx2.
__device__ __align__(16) float g_emi[2][EMP_SZ * 4];   // 67 MB

// -------------------------------------------------------------------------
// Canonicalize inputs (bf16/fp32 autodetect via mask). Gate permutation:
// row n' = 4u+g  <->  original torch gate row g*128+u.
// Also zero-fills the output buffer (folded fill_out).
// -------------------------------------------------------------------------
__global__ __launch_bounds__(256) void convert_kernel(
    const void* mask, const void* emb,
    const void* wih_f, const void* whh_f, const void* bih_f, const void* bhh_f,
    const void* wih_b, const void* whh_b, const void* bih_b, const void* bhh_b,
    const void* wout, const void* bout, const void* trans,
    const void* startt, const void* endt, float* out, int out_size)
{
    const bool isb = (((const unsigned*)mask)[0] == 0x3F803F80u);
    auto ldf = [&](const void* p, long i) -> float {
        float v = isb ? bf2f(((const __hip_bfloat16*)p)[i]) : ((const float*)p)[i];
        return scrub0(v);
    };
    const long tid0   = (long)blockIdx.x * blockDim.x + threadIdx.x;
    const long stride = (long)gridDim.x * blockDim.x;

    for (long i = tid0; i < out_size; i += stride) out[i] = 0.f;

    // embedding: vectorized 8-wide (VOCAB*E_DIM = 640128, divisible by 8)
    if (isb) {
        const u16x8* src = (const u16x8*)emb;
        u16x8* dst = (u16x8*)g_emb;
        for (long i = tid0; i < (long)VOCAB * E_DIM / 8; i += stride) {
            u16x8 v = src[i];
            #pragma unroll
            for (int j = 0; j < 8; j++)
                if (((v[j] >> 7) & 0xFFu) == 0xFFu) v[j] = 0;
            dst[i] = v;
        }
    } else {
        const float4* src = (const float4*)emb;
        for (long i = tid0; i < (long)VOCAB * E_DIM / 4; i += stride) {
            const float4 v = src[i];
            __hip_bfloat16* d = &g_emb[i * 4];
            d[0] = __float2bfloat16(scrub0(v.x));
            d[1] = __float2bfloat16(scrub0(v.y));
            d[2] = __float2bfloat16(scrub0(v.z));
            d[3] = __float2bfloat16(scrub0(v.w));
        }
    }
    for (long i = tid0; i < (long)G4 * E_DIM; i += stride) {
        const int np = (int)(i >> 7), e = (int)(i & 127);
        const int g = np & 3, u = np >> 2;
        const long src = (long)(g * 128 + u) * E_DIM + e;
        g_wih[0][i] = __float2bfloat16(ldf(wih_f, src));
        g_wih[1][i] = __float2bfloat16(ldf(wih_b, src));
    }
    for (long i = tid0; i < (long)G4 * HHID; i += stride) {
        const int np = (int)(i >> 7), k = (int)(i & 127);
        const int g = np & 3, u = np >> 2;
        const long src = (long)(g * 128 + u) * HHID + k;
        g_whh2[0][i] = __float2bfloat16(ldf(whh_f, src));
        g_whh2[1][i] = __float2bfloat16(ldf(whh_b, src));
    }
    for (long i = tid0; i < G4; i += stride) {
        const int g = (int)i & 3, u = (int)i >> 2;
        const long src = g * 128 + u;
        g_bias[0][i] = ldf(bih_f, src) + ldf(bhh_f, src);
        g_bias[1][i] = ldf(bih_b, src) + ldf(bhh_b, src);
    }
    for (long i = tid0; i < T_TAG * 256; i += stride) g_wout[i] = ldf(wout, i);
    for (long i = tid0; i < T_TAG * T_TAG; i += stride) g_trans[i] = ldf(trans, i);
    for (long i = tid0; i < T_TAG; i += stride) {
        g_bout[i]  = ldf(bout, i);
        g_start[i] = ldf(startt, i);
        g_end[i]   = ldf(endt, i);
    }
    for (long i = tid0; i < (long)B_SZ * S_LEN; i += stride)
        g_maskf[i] = ldf(mask, i);
}

// -------------------------------------------------------------------------
// Per-VOCAB input projection: pxv[dir][v] = bias + Wih'@emb[v]^T. MFMA
// columns = 16 tokens per block. Grid (313 token-groups, 2 dir).
// -------------------------------------------------------------------------
__global__ __launch_bounds__(512, 2) void pxv_gemm()
{
    const int grp = blockIdx.x, dir = blockIdx.y;
    const int tid  = threadIdx.x;
    const int lane = tid & 63, wv = tid >> 6;
    const int m16  = lane & 15, quad = lane >> 4;

    bf16x8 V[4][4];
    f32x4 bias4[4];
    #pragma unroll
    for (int t = 0; t < 4; t++) {
        const int np = (wv * 4 + t) * 16 + m16;
        #pragma unroll
        for (int kk = 0; kk < 4; kk++)
            V[t][kk] = *(const bf16x8*)&g_wih[dir][(long)np * E_DIM + kk * 32 + quad * 8];
        const int u = 16 * wv + 4 * t + quad;
        const float4 b4 = *(const float4*)&g_bias[dir][4 * u];
        bias4[t] = (f32x4){b4.x, b4.y, b4.z, b4.w};
    }
    const int v  = grp * 16 + m16;
    const int vv = (v < VOCAB) ? v : 0;
    bf16x8 E[4];
    #pragma unroll
    for (int kk = 0; kk < 4; kk++)
        E[kk] = *(const bf16x8*)&g_emb[(long)vv * E_DIM + kk * 32 + quad * 8];
    #pragma unroll
    for (int t = 0; t < 4; t++) {
        f32x4 px = bias4[t];
        #pragma unroll
        for (int kk = 0; kk < 4; kk++)
            px = __builtin_amdgcn_mfma_f32_16x16x32_bf16(V[t][kk], E[kk], px, 0, 0, 0);
        const int u = 16 * wv + 4 * t + quad;
        if (v < VOCAB)
            *(f32x4*)&g_pxv[((long)(dir * VOCABP + v) * 128 + u) * 4] = px;
    }
}

// -------------------------------------------------------------------------
// Recurrence MFMA scan (R5 structure) + fused emission with LDS COMBINE:
// waves 0-3 ds_write their cross-term partials into emL[step&1] (8KB parity
// buffer); after the step barrier (visibility via the existing lgkmcnt(0))
// ALL 8 waves stream the combined 4KB block out as coalesced dwordx2 into
// the interleaved g_emi layout. Write-out lags TWO steps (emg2<-emg1<-emg0);
// epilogue flushes positions 510 and 511. Same partials + same viterbi sum
// order as R11 -> scores bit-identical. Recurrent path identical to R5.
// -------------------------------------------------------------------------
#define SCAN_STEP(RD, PX)                                                      \
  {                                                                            \
    const int wr_ = (RD) ^ 1;                                                  \
    /* write-out of step itv-2's combined partials (written to emL[RD^1]) */   \
    if (itv >= 2) {                                                            \
        const float2 wo_ = *(const float2*)&emL[(RD) ^ 1][tid * 2];            \
        *(float2*)emg2 = wo_;                                                  \
    }                                                                          \
    /* early: offset+address for the step+2 gather (latency hides below) */    \
    int se2_ = sev + 2 * step;                                                 \
    se2_ = se2_ < 0 ? 0 : (se2_ > S_LEN - 1 ? S_LEN - 1 : se2_);               \
    const float* pf_ = pxvL + xO[se2_ * 16 + m16];                             \
    bf16x8 Hh_[4], Hl_[4];                                                     \
    _Pragma("unroll")                                                          \
    for (int kk = 0; kk < 4; kk++) {                                           \
        const int off_ = ((kk * 4 + quad) * 16 + m16) * 8;                     \
        Hh_[kk] = *(const bf16x8*)&hB[RD][0][off_];                            \
        Hl_[kk] = *(const bf16x8*)&hB[RD][1][off_];                            \
    }                                                                          \
    _Pragma("unroll")                                                          \
    for (int t = 0; t < 4; t++) {                                              \
        _Pragma("unroll")                                                      \
        for (int kk = 0; kk < 4; kk++) {                                       \
            PX[t] = __builtin_amdgcn_mfma_f32_16x16x32_bf16(W[t][kk], Hh_[kk], PX[t], 0, 0, 0); \
            PX[t] = __builtin_amdgcn_mfma_f32_16x16x32_bf16(W[t][kk], Hl_[kk], PX[t], 0, 0, 0); \
        }                                                                      \
    }                                                                          \
    /* fused emission partial from h(prev step) -> emL[RD] (combine buffer) */ \
    if (wv < 4 && itv) {                                                       \
        f32x4 em_ = {0.f, 0.f, 0.f, 0.f};                                      \
        _Pragma("unroll")                                                      \
        for (int kk = 0; kk < 4; kk++)                                         \
            em_ = __builtin_amdgcn_mfma_f32_16x16x32_bf16(                     \
                WA[kk], (wv & 1) ? Hl_[kk] : Hh_[kk], em_, 0, 0, 0);           \
        emL[RD][ebase]       = em_[0];                                         \
        emL[RD][ebase + 64]  = em_[1];                                         \
        emL[RD][ebase + 128] = em_[2];                                         \
        emL[RD][ebase + 192] = em_[3];                                         \
    }                                                                          \
    _Pragma("unroll")                                                          \
    for (int t = 0; t < 4; t++) {                                              \
        const float iv = fsig(PX[t][0]);                                       \
        const float fv = fsig(PX[t][1]);                                       \
        const float gv = ftanh(PX[t][2]);                                      \
        const float ov = fsig(PX[t][3]);                                       \
        c[t] = fv * c[t] + iv * gv;                                            \
        const float h = ov * ftanh(c[t]);                                      \
        const int u = 16 * wv + 4 * t + quad;                                  \
        const unsigned ub = __float_as_uint(h);                                \
        const unsigned hb_ = ub >> 16;                                         \
        const float hif = __uint_as_float(ub & 0xFFFF0000u);                   \
        const unsigned lb_ = __float_as_uint(h - hif) >> 16;                   \
        const int ha = (u >> 3) * 128 + m16 * 8 + (u & 7);                     \
        hB[wr_][0][ha] = (unsigned short)hb_;                                  \
        hB[wr_][1][ha] = (unsigned short)lb_;                                  \
    }                                                                          \
    {   /* gather PX for step itv+2 — address precomputed at step top */       \
        PX[0] = *(const f32x4*)(pf_ + 0);                                      \
        PX[1] = *(const f32x4*)(pf_ + 16);                                     \
        PX[2] = *(const f32x4*)(pf_ + 32);                                     \
        PX[3] = *(const f32x4*)(pf_ + 48);                                     \
    }                                                                          \
    asm volatile("s_waitcnt lgkmcnt(0)" ::: "memory");                         \
    __builtin_amdgcn_sched_barrier(0);                                         \
    __builtin_amdgcn_s_barrier();                                              \
    __builtin_amdgcn_sched_barrier(0);                                         \
    emg2 = emg1; emg1 = emg0; emg0 += emgd;                                    \
    sev += step; itv++;                                                        \
  }

__global__ __launch_bounds__(512, 2) void scan_mfma(const int* __restrict__ x)
{
    __shared__ __align__(16) unsigned short hB[2][2][16 * 16 * 8];  // 16 KB
    __shared__ int xO[S_LEN * 16];   // token * 512 (pxv element offset), 32 KB
    __shared__ __align__(16) float emL[2][1024];   // 8 KB emission combine

    const int bg = blockIdx.x, dir = blockIdx.y;
    const int tid  = threadIdx.x;
    const int lane = tid & 63, wv = tid >> 6;        // wv 0..7
    const int m16  = lane & 15, quad = lane >> 4;
    const int ebase = quad * 256 + m16 * 4 + (wv & 3);   // emL write base

    // persistent A fragments: Whh' rows (4 tiles of 16 rows per wave)
    bf16x8 W[4][4];
    #pragma unroll
    for (int t = 0; t < 4; t++) {
        const int np = (wv * 4 + t) * 16 + m16;
        #pragma unroll
        for (int kk = 0; kk < 4; kk++)
            W[t][kk] = *(const bf16x8*)&g_whh2[dir][(long)np * HHID + kk * 32 + quad * 8];
    }
    // Wout A-fragments for the fused emission (waves 0-3 only): A row = m16
    // (tag j, zero-padded j>=9), k = kk*32+quad*8+elem — identical k mapping
    // to the recurrent fragments. wv 0,1 hold the hi-split, wv 2,3 the lo.
    bf16x8 WA[4];
    if (wv < 4) {
        #pragma unroll
        for (int kk = 0; kk < 4; kk++) {
            #pragma unroll
            for (int j = 0; j < 8; j++) {
                const float w = (m16 < T_TAG)
                    ? g_wout[m16 * 256 + dir * 128 + kk * 32 + quad * 8 + j] : 0.f;
                const unsigned uw  = __float_as_uint(w);
                const unsigned hib = uw >> 16;
                const float hif    = __uint_as_float(uw & 0xFFFF0000u);
                const unsigned lob = __float_as_uint(w - hif) >> 16;
                WA[kk][j] = (short)((wv < 2) ? hib : lob);
            }
        }
    }
    {   // stage token offsets: xO[s*16+m] = x[bg*16+m][s] * 512
        const bool x64 = ((x[1] | x[3] | x[5] | x[7]) == 0);
        for (int i = tid; i < S_LEN * 16; i += 512) {
            const int s = i >> 4, m = i & 15;
            const int ii = (bg * 16 + m) * S_LEN + s;
            int tok = x64 ? x[2 * ii] : x[ii];
            tok = (unsigned)tok < VOCAB ? tok : 0;
            xO[i] = tok * 512;
        }
    }
    for (int i = tid; i < 2 * 2 * 2048; i += 512) ((unsigned short*)hB)[i] = 0;
    float c[4] = {0.f, 0.f, 0.f, 0.f};
    __syncthreads();

    const int se0  = dir ? (S_LEN - 1) : 0;
    const int step = dir ? -1 : 1;
    const int u0   = 16 * wv + quad;

    // pxv lane base: element ((dir*VOCABP + v)*128 + u)*4; v enters via xO
    const float* pxvL = &g_pxv[(long)dir * VOCABP * 512 + u0 * 4];

    f32x4 pxA[4], pxB[4];
    {
        const int o0 = xO[se0 * 16 + m16];
        #pragma unroll
        for (int t = 0; t < 4; t++) pxA[t] = *(const f32x4*)(pxvL + o0 + 16 * t);
        const int se1 = (S_LEN > 1) ? se0 + step : se0;
        const int o1 = xO[se1 * 16 + m16];
        #pragma unroll
        for (int t = 0; t < 4; t++) pxB[t] = *(const f32x4*)(pxvL + o1 + 16 * t);
    }

    // emission write-out pointers (2-step lag): block base for step s is
    // g_emi[dir] + (s*16+bg)*1024; each thread streams 2 floats (dwordx2).
    float* emg0 = &g_emi[dir][((long)(se0 * 16 + bg)) * 1024 + tid * 2];
    const long emgd = (long)step * 16384;
    float* emg1 = emg0;
    float* emg2 = emg0;

    int itv = 0, sev = se0;

    for (int it = 0; it < S_LEN; it += 2) {
        SCAN_STEP(0, pxA)      // even step: read hB[0], write hB[1]
        SCAN_STEP(1, pxB)      // odd step:  read hB[1], write hB[0]
    }

    // epilogue A: flush position 510 — its combined partials sit in emL[1]
    // (written at itv=511), visible after the loop's terminal barrier.
    {
        const float2 wo_ = *(const float2*)&emL[1][tid * 2];
        *(float2*)emg2 = wo_;     // emg2 == base(pos 510)
    }
    // epilogue B: emit the FINAL step's h (in hB[0]) -> emL[0] -> pos 511.
    if (wv < 4) {
        bf16x8 Hh_[4], Hl_[4];
        #pragma unroll
        for (int kk = 0; kk < 4; kk++) {
            const int off_ = ((kk * 4 + quad) * 16 + m16) * 8;
            Hh_[kk] = *(const bf16x8*)&hB[0][0][off_];
            Hl_[kk] = *(const bf16x8*)&hB[0][1][off_];
        }
        f32x4 em_ = {0.f, 0.f, 0.f, 0.f};
        #pragma unroll
        for (int kk = 0; kk < 4; kk++)
            em_ = __builtin_amdgcn_mfma_f32_16x16x32_bf16(
                WA[kk], (wv & 1) ? Hl_[kk] : Hh_[kk], em_, 0, 0, 0);
        emL[0][ebase]       = em_[0];
        emL[0][ebase + 64]  = em_[1];
        emL[0][ebase + 128] = em_[2];
        emL[0][ebase + 192] = em_[3];
    }
    asm volatile("s_waitcnt lgkmcnt(0)" ::: "memory");
    __builtin_amdgcn_sched_barrier(0);
    __builtin_amdgcn_s_barrier();
    __builtin_amdgcn_sched_barrier(0);
    {
        const float2 wo_ = *(const float2*)&emL[0][tid * 2];
        *(float2*)emg1 = wo_;     // emg1 == base(pos 511)
    }
}

// -------------------------------------------------------------------------
// Viterbi: 1 wave per block (grid 256). Lanes 0..8 = tags.
// R15: (1) XCD-affinity swizzle — all 16 blocks sharing a bg (which read
// interleaved 16B pieces of the same 4KB g_emi chunks) land on ONE XCD's
// L2 (b = (bb&7)*32 + bb>>3; fixed bg => bb ≡ bg>>1 mod 8); (2) emission
// prefetch depth 4 (covers ~500cy L3 latency); (3) mask staged in LDS.
// Partial summation order identical to R11/R14 — scores bit-identical.
// -------------------------------------------------------------------------
#define VLOAD(S, A, C, M)                                                      \
  {                                                                            \
    const long e_ = ((long)((S) * 16 + bg) * 256 + jj * 16 + mm) << 2;         \
    A = *(const f32x4*)&g_emi[0][e_];                                          \
    C = *(const f32x4*)&g_emi[1][e_];                                          \
    M = mL[(S)];                                                               \
  }

#define VSTEP(S, A, C, M)                                                      \
  {                                                                            \
    const float e = scrub0(boj + (((A[0] + A[1]) + (A[2] + A[3]))              \
                                + ((C[0] + C[1]) + (C[2] + C[3]))));           \
    float best = score[0] + tcol[0];                                           \
    int arg = 0;                                                               \
    _Pragma("unroll")                                                          \
    for (int i = 1; i < T_TAG; i++) {                                          \
        const float cnd = score[i] + tcol[i];                                  \
        if (cnd > best) { best = cnd; arg = i; }                               \
    }                                                                          \
    float ns; int nbp;                                                         \
    if (M > 0.f) { ns = best + e * M; nbp = arg; }                             \
    else         { ns = score[jj];    nbp = jj;  }                             \
    if (lane < T_TAG) bp[S][jj] = (unsigned char)nbp;                          \
    _Pragma("unroll")                                                          \
    for (int i = 0; i < T_TAG; i++) score[i] = __shfl(ns, i, 64);              \
  }

__global__ __launch_bounds__(64, 1)
void viterbi_kernel(float* __restrict__ out, int out_size)
{
    __shared__ unsigned char bp[S_LEN][T_TAG];
    __shared__ float mL[S_LEN];
    const int lane = threadIdx.x;
    const int bb = blockIdx.x;
    const int b  = (bb & 7) * 32 + (bb >> 3);   // XCD-affinity swizzle
    const int jj = (lane < T_TAG) ? lane : 0;
    const int bg = b >> 4, mm = b & 15;

    for (int i = lane; i < S_LEN; i += 64) mL[i] = g_maskf[b * S_LEN + i];
    __syncthreads();

    float tcol[T_TAG];
    #pragma unroll
    for (int i = 0; i < T_TAG; i++) tcol[i] = g_trans[i * T_TAG + jj];
    const float boj = g_bout[jj];

    float score[T_TAG];
    {
        const float m0 = mL[0];
        #pragma unroll
        for (int i = 0; i < T_TAG; i++) {
            const long o = ((long)bg * 256 + i * 16 + mm) << 2;
            const f32x4 A = *(const f32x4*)&g_emi[0][o];
            const f32x4 C = *(const f32x4*)&g_emi[1][o];
            const float s8 = (((A[0] + A[1]) + (A[2] + A[3]))
                            + ((C[0] + C[1]) + (C[2] + C[3])));
            score[i] = g_start[i] + scrub0(g_bout[i] + s8) * m0;
        }
    }

    f32x4 a0, c0, a1, c1, a2, c2, a3, c3;
    f32x4 n0a, n0c, n1a, n1c, n2a, n2c, n3a, n3c;
    float m0_, m1_, m2_, m3_, n0m, n1m, n2m, n3m;
    VLOAD(1, a0, c0, m0_)
    VLOAD(2, a1, c1, m1_)
    VLOAD(3, a2, c2, m2_)
    VLOAD(4, a3, c3, m3_)

    for (int s = 1; s < S_LEN; s += 4) {
        const int p0 = (s + 4 < S_LEN) ? s + 4 : s;
        VLOAD(p0, n0a, n0c, n0m)
        VSTEP(s, a0, c0, m0_)
        const int p1 = (s + 5 < S_LEN) ? s + 5 : s;
        VLOAD(p1, n1a, n1c, n1m)
        if (s + 1 < S_LEN) VSTEP(s + 1, a1, c1, m1_)
        const int p2 = (s + 6 < S_LEN) ? s + 6 : s;
        VLOAD(p2, n2a, n2c, n2m)
        if (s + 2 < S_LEN) VSTEP(s + 2, a2, c2, m2_)
        const int p3 = (s + 7 < S_LEN) ? s + 7 : s;
        VLOAD(p3, n3a, n3c, n3m)
        if (s + 3 < S_LEN) VSTEP(s + 3, a3, c3, m3_)
        a0 = n0a; c0 = n0c; m0_ = n0m;
        a1 = n1a; c1 = n1c; m1_ = n1m;
        a2 = n2a; c2 = n2c; m2_ = n2m;
        a3 = n3a; c3 = n3c; m3_ = n3m;
    }
    #pragma unroll
    for (int i = 0; i < T_TAG; i++) score[i] += g_end[i];

    __syncthreads();   // bp visible for backtrace

    if (lane == 0) {
        float bs = score[0]; int last = 0;
        #pragma unroll
        for (int i = 1; i < T_TAG; i++)
            if (score[i] > bs) { bs = score[i]; last = i; }
        {
            const unsigned u = __float_as_uint(bs);
            if (((u >> 23) & 0xFFu) == 0xFFu) bs = -100.f;
        }
        if ((long)B_SZ * S_LEN + b < out_size)
            out[(long)B_SZ * S_LEN + b] = bs;
        int tag = last;
        if (tag < 0) tag = 0; if (tag > 8) tag = 8;
        out[(long)b * S_LEN + (S_LEN - 1)] = (float)tag;
        for (int s2 = S_LEN - 1; s2 >= 1; s2--) {
            tag = bp[s2][tag];
            if (tag < 0) tag = 0; if (tag > 8) tag = 8;
            out[(long)b * S_LEN + (s2 - 1)] = (float)tag;
        }
    }
}

// -------------------------------------------------------------------------
extern "C" void kernel_launch(void* const* d_in, const int* in_sizes, int n_in,
                              void* d_out, int out_size, void* d_ws, size_t ws_size,
                              hipStream_t stream) {
    const int* x = (const int*)d_in[0];
    float* out = (float*)d_out;

    convert_kernel<<<512, 256, 0, stream>>>(
        d_in[1], d_in[2], d_in[3], d_in[4], d_in[5], d_in[6],
        d_in[7], d_in[8], d_in[9], d_in[10], d_in[11], d_in[12],
        d_in[13], d_in[14], d_in[15], out, out_size);
    pxv_gemm<<<dim3((VOCABP / 16), 2), 512, 0, stream>>>();
    scan_mfma<<<dim3(16, 2), 512, 0, stream>>>(x);
    viterbi_kernel<<<256, 64, 0, stream>>>(out, out_size);
}